// Round 3
// baseline (16062.109 us; speedup 1.0000x reference)
//
#include <hip/hip_runtime.h>
#include <math.h>

// ---------------------------------------------------------------------------
// Round 3: ws-overflow discriminator. Round1 (optimized) and Round2 (naive)
// gave bit-identical absmax=0.2227 -> shared cause. Both used a 56.6 MB
// workspace peak without checking ws_size. This build keeps Round2's naive
// kernels semantically identical but chunks the conv pipeline over the batch
// so peak ws usage is <= 12.3 MB (adaptive down to ~6 MB via ws_size).
// ---------------------------------------------------------------------------

#define BN_EPS 1e-5f

// ---- conv1 chunk: x(512,1,72,64) -> out1_c(nb,16,36,32) -------------------
__global__ __launch_bounds__(256) void conv1_c(
    const float* __restrict__ x, const float* __restrict__ w,
    const float* __restrict__ bias, const float* __restrict__ g,
    const float* __restrict__ bt, const float* __restrict__ m,
    const float* __restrict__ v, float* __restrict__ out1,
    int nb0, int nb)
{
    int t = blockIdx.x * 256 + threadIdx.x;
    if (t >= nb * 16 * 36 * 32) return;
    int pw = t & 31;
    int r  = t >> 5;
    int ph = r % 36; r /= 36;
    int oc = r & 15;
    int nl = r >> 4;

    const float* xn = x + (size_t)(nb0 + nl) * 4608;
    const float* wp = w + oc * 24;                 // w[oc][0][kh][kw]
    float scale = g[oc] / sqrtf(v[oc] + BN_EPS);
    float mean = m[oc], beta = bt[oc], b = bias[oc];

    float mx = -3.4e38f;
    for (int py = 0; py < 2; ++py) {
        for (int px = 0; px < 2; ++px) {
            int oh = 2 * ph + py, ow = 2 * pw + px;
            float a = 0.f;
            for (int kh = 0; kh < 6; ++kh) {
                int iy = oh + kh - 2;              // pad_h_lo = 2
                if (iy < 0 || iy >= 72) continue;
                for (int kw = 0; kw < 4; ++kw) {
                    int ix = ow + kw - 1;          // pad_w_lo = 1
                    if (ix < 0 || ix >= 64) continue;
                    a = fmaf(xn[iy * 64 + ix], wp[kh * 4 + kw], a);
                }
            }
            float val = fmaxf(a + b, 0.f);
            val = (val - mean) * scale + beta;
            mx = fmaxf(mx, val);
        }
    }
    out1[t] = mx;                                  // chunk-local (nl,oc,ph,pw)
}

// ---- conv2 chunk: out1_c(nb,16,36,32) -> out2_c(nb,32,18,16) --------------
__global__ __launch_bounds__(256) void conv2_c(
    const float* __restrict__ in, const float* __restrict__ w,
    const float* __restrict__ bias, const float* __restrict__ g,
    const float* __restrict__ bt, const float* __restrict__ m,
    const float* __restrict__ v, float* __restrict__ out2, int nb)
{
    int t = blockIdx.x * 256 + threadIdx.x;
    if (t >= nb * 32 * 18 * 16) return;
    int pw = t & 15;
    int r  = t >> 4;
    int ph = r % 18; r /= 18;
    int oc = r & 31;
    int nl = r >> 5;

    const float* inn = in + (size_t)nl * 16 * 1152;
    const float* wo  = w + oc * 16 * 24;           // w[oc][ic][kh][kw]
    float scale = g[oc] / sqrtf(v[oc] + BN_EPS);
    float mean = m[oc], beta = bt[oc], b = bias[oc];

    float mx = -3.4e38f;
    for (int py = 0; py < 2; ++py) {
        for (int px = 0; px < 2; ++px) {
            int oh = 2 * ph + py, ow = 2 * pw + px;
            float a = 0.f;
            for (int ic = 0; ic < 16; ++ic) {
                const float* ci = inn + ic * 1152;
                const float* wi = wo + ic * 24;
                for (int kh = 0; kh < 6; ++kh) {
                    int iy = oh + kh - 2;
                    if (iy < 0 || iy >= 36) continue;
                    for (int kw = 0; kw < 4; ++kw) {
                        int ix = ow + kw - 1;
                        if (ix < 0 || ix >= 32) continue;
                        a = fmaf(ci[iy * 32 + ix], wi[kh * 4 + kw], a);
                    }
                }
            }
            float val = fmaxf(a + b, 0.f);
            val = (val - mean) * scale + beta;
            mx = fmaxf(mx, val);
        }
    }
    out2[t] = mx;                                  // chunk-local (nl,oc,ph,pw)
}

// ---- conv3 chunk: out2_c(nb,32,18,16) -> out3 GLOBAL (512,1536) -----------
__global__ __launch_bounds__(256) void conv3_c(
    const float* __restrict__ in, const float* __restrict__ w,
    const float* __restrict__ bias, const float* __restrict__ g,
    const float* __restrict__ bt, const float* __restrict__ m,
    const float* __restrict__ v, float* __restrict__ out3,
    int nb0, int nb)
{
    int t = blockIdx.x * 256 + threadIdx.x;
    if (t >= nb * 64 * 24) return;
    int pp = t % 24;
    int r  = t / 24;
    int oc = r & 63;
    int nl = r >> 6;
    int pph = pp >> 2, ppw = pp & 3;               // pool 3x4 over 18x16

    const float* inn = in + (size_t)nl * 32 * 288;
    const float* wo  = w + oc * 32 * 24;           // w[oc][ic][kh][kw]
    float scale = g[oc] / sqrtf(v[oc] + BN_EPS);
    float mean = m[oc], beta = bt[oc], b = bias[oc];

    float mx = -3.4e38f;
    for (int dy = 0; dy < 3; ++dy) {
        for (int dx = 0; dx < 4; ++dx) {
            int oh = pph * 3 + dy, ow = ppw * 4 + dx;
            float a = 0.f;
            for (int ic = 0; ic < 32; ++ic) {
                const float* ci = inn + ic * 288;
                const float* wi = wo + ic * 24;
                for (int kh = 0; kh < 6; ++kh) {
                    int iy = oh + kh - 2;
                    if (iy < 0 || iy >= 18) continue;
                    for (int kw = 0; kw < 4; ++kw) {
                        int ix = ow + kw - 1;
                        if (ix < 0 || ix >= 16) continue;
                        a = fmaf(ci[iy * 16 + ix], wi[kh * 4 + kw], a);
                    }
                }
            }
            float val = fmaxf(a + b, 0.f);
            val = (val - mean) * scale + beta;
            mx = fmaxf(mx, val);
        }
    }
    // flatten: f = oc*24 + pph*4 + ppw
    out3[(size_t)(nb0 + nl) * 1536 + oc * 24 + pp] = mx;
}

// ---- fc: out(B,N) = BN(relu(A(B,K) @ W(N,K)^T + b)). One thread/output. ---
__global__ __launch_bounds__(256) void fc_naive(
    const float* __restrict__ A, const float* __restrict__ W,
    const float* __restrict__ bias, const float* __restrict__ g,
    const float* __restrict__ bt, const float* __restrict__ m,
    const float* __restrict__ v, float* __restrict__ out,
    int K, int N, int total)
{
    int t = blockIdx.x * 256 + threadIdx.x;
    if (t >= total) return;
    int o = t % N;
    int n = t / N;
    const float* ar = A + (size_t)n * K;
    const float* wr = W + (size_t)o * K;
    float a = 0.f;
    for (int k = 0; k < K; ++k) a = fmaf(ar[k], wr[k], a);
    float val = fmaxf(a + bias[o], 0.f);
    out[t] = (val - m[o]) * (g[o] / sqrtf(v[o] + BN_EPS)) + bt[o];
}

// ---- row L2 normalize, emit sq = sum(E^2) ---------------------------------
__global__ __launch_bounds__(128) void norm_naive(const float* __restrict__ f3,
                                                  float* __restrict__ E,
                                                  float* __restrict__ sq)
{
    __shared__ float red[128];
    int row = blockIdx.x, tid = threadIdx.x;
    float vv = f3[row * 128 + tid];
    red[tid] = vv * vv;
    __syncthreads();
    for (int s = 64; s > 0; s >>= 1) {
        if (tid < s) red[tid] += red[tid + s];
        __syncthreads();
    }
    float total = red[0];
    float nn = fmaxf(sqrtf(total), 1e-12f);
    E[row * 128 + tid] = vv / nn;
    if (tid == 0) sq[row] = total / (nn * nn);
}

// ---- pairwise distance + global max ---------------------------------------
__global__ __launch_bounds__(256) void dist_naive(const float* __restrict__ E,
                                                  const float* __restrict__ sq,
                                                  float* __restrict__ D,
                                                  unsigned* __restrict__ mxslot)
{
    __shared__ float red[256];
    int t = blockIdx.x * 256 + threadIdx.x;
    int j = t & 511, i = t >> 9;
    const float* Ei = E + i * 128;
    const float* Ej = E + j * 128;
    float dot = 0.f;
    for (int k = 0; k < 128; ++k) dot = fmaf(Ei[k], Ej[k], dot);
    float d2 = sq[i] + sq[j] - 2.f * dot;
    float dist = sqrtf(fmaxf(d2, 1e-12f));
    dist = (d2 > 0.f) ? dist : 0.f;
    if (i == j) dist = 0.f;                        // exact-0 diag (matches ref)
    D[t] = dist;

    int tid = threadIdx.x;
    red[tid] = dist;
    __syncthreads();
    for (int s = 128; s > 0; s >>= 1) {
        if (tid < s) red[tid] = fmaxf(red[tid], red[tid + s]);
        __syncthreads();
    }
    if (tid == 0) atomicMax(mxslot, __float_as_uint(red[0]));  // dist >= 0
}

__global__ __launch_bounds__(256) void scale_naive(float* __restrict__ D,
                                                   const unsigned* __restrict__ mxslot)
{
    int idx = blockIdx.x * 256 + threadIdx.x;
    float M = __uint_as_float(*mxslot);
    D[idx] = D[idx] / M;
}

// ---------------------------------------------------------------------------
extern "C" void kernel_launch(void* const* d_in, const int* in_sizes, int n_in,
                              void* d_out, int out_size, void* d_ws, size_t ws_size,
                              hipStream_t stream)
{
    (void)in_sizes; (void)n_in; (void)out_size;
    const float* x   = (const float*)d_in[0];
    const float* c1w = (const float*)d_in[1];
    const float* c1b = (const float*)d_in[2];
    const float* g1  = (const float*)d_in[3];
    const float* b1  = (const float*)d_in[4];
    const float* m1  = (const float*)d_in[5];
    const float* v1  = (const float*)d_in[6];
    const float* c2w = (const float*)d_in[7];
    const float* c2b = (const float*)d_in[8];
    const float* g2  = (const float*)d_in[9];
    const float* b2  = (const float*)d_in[10];
    const float* m2  = (const float*)d_in[11];
    const float* v2  = (const float*)d_in[12];
    const float* c3w = (const float*)d_in[13];
    const float* c3b = (const float*)d_in[14];
    const float* g3  = (const float*)d_in[15];
    const float* b3  = (const float*)d_in[16];
    const float* m3  = (const float*)d_in[17];
    const float* v3  = (const float*)d_in[18];
    const float* f1w = (const float*)d_in[19];
    const float* f1b = (const float*)d_in[20];
    const float* gf1 = (const float*)d_in[21];
    const float* bf1 = (const float*)d_in[22];
    const float* mf1 = (const float*)d_in[23];
    const float* vf1 = (const float*)d_in[24];
    const float* f2w = (const float*)d_in[25];
    const float* f2b = (const float*)d_in[26];
    const float* gf2 = (const float*)d_in[27];
    const float* bf2 = (const float*)d_in[28];
    const float* mf2 = (const float*)d_in[29];
    const float* vf2 = (const float*)d_in[30];
    const float* f3w = (const float*)d_in[31];
    const float* f3b = (const float*)d_in[32];
    const float* gf3 = (const float*)d_in[33];
    const float* bf3 = (const float*)d_in[34];
    const float* mf3 = (const float*)d_in[35];
    const float* vf3 = (const float*)d_in[36];

    float* ws = (float*)d_ws;
    // ---- persistent region (floats): 5.0 MB total -------------------------
    float* out3 = ws + 0;            // 512*1536 = 786432
    float* f1   = ws + 786432;       // 512*512  = 262144
    float* f2   = ws + 1048576;      // 512*256  = 131072
    float* f3   = ws + 1179648;      // 512*128  = 65536
    float* E    = ws + 1245184;      // 512*128  = 65536
    float* sq   = ws + 1310720;      // 512
    unsigned* mx = (unsigned*)(ws + 1311232);
    const size_t CH0 = 1311296;      // chunk buffers start (64-aligned)

    // ---- pick batch-chunk size from ws_size (deterministic every call) ----
    // per-batch chunk floats: out1 = 16*36*32 = 18432, out2 = 32*18*16 = 9216
    int Bc = 64;                     // forced cap: peak 12.3 MB even if ws huge
    while (Bc > 4 && (CH0 + (size_t)Bc * 27648) * 4 > ws_size) Bc >>= 1;
    float* out1c = ws + CH0;                         // Bc*18432 floats
    float* out2c = ws + CH0 + (size_t)Bc * 18432;    // Bc*9216 floats

    float* out = (float*)d_out;

    hipMemsetAsync(mx, 0, 4, stream);
    for (int nb0 = 0; nb0 < 512; nb0 += Bc) {
        int g1n = (Bc * 18432 + 255) / 256;
        int g2n = (Bc * 9216 + 255) / 256;
        int g3n = (Bc * 1536 + 255) / 256;
        conv1_c<<<g1n, 256, 0, stream>>>(x, c1w, c1b, g1, b1, m1, v1, out1c, nb0, Bc);
        conv2_c<<<g2n, 256, 0, stream>>>(out1c, c2w, c2b, g2, b2, m2, v2, out2c, Bc);
        conv3_c<<<g3n, 256, 0, stream>>>(out2c, c3w, c3b, g3, b3, m3, v3, out3, nb0, Bc);
    }
    fc_naive<<<1024, 256, 0, stream>>>(out3, f1w, f1b, gf1, bf1, mf1, vf1, f1, 1536, 512, 262144);
    fc_naive<<<512, 256, 0, stream>>>(f1, f2w, f2b, gf2, bf2, mf2, vf2, f2, 512, 256, 131072);
    fc_naive<<<256, 256, 0, stream>>>(f2, f3w, f3b, gf3, bf3, mf3, vf3, f3, 256, 128, 65536);
    norm_naive<<<512, 128, 0, stream>>>(f3, E, sq);
    dist_naive<<<1024, 256, 0, stream>>>(E, sq, out, mx);
    scale_naive<<<1024, 256, 0, stream>>>(out, mx);
}

// Round 4
// 2294.917 us; speedup vs baseline: 6.9990x; 6.9990x over previous
//
#include <hip/hip_runtime.h>
#include <math.h>

// ---------------------------------------------------------------------------
// Round 4: Round-1 optimized kernels (proven semantically correct by the
// R1==R2 bit-identical-failure + R3-naive-pass argument) restored on top of
// the R3 chunked workspace (ws overflow was the real bug; peak <= 12.6 MB,
// adaptive down via ws_size). Convs: LDS input staging + [ic][ky][kx][oc]
// repacked weights (wave-uniform -> SGPR broadcast). FC: 64x64 LDS tiles.
// ---------------------------------------------------------------------------

#define BN_EPS 1e-5f

// ---------------- weight repack: w[oc][ic][ky][kx] -> wT[ic*ky*kx][oc] -----
__global__ void repack_k(const float* __restrict__ w2, const float* __restrict__ w3,
                         float* __restrict__ wT2, float* __restrict__ wT3) {
    int t = blockIdx.x * 256 + threadIdx.x;
    if (t < 12288) wT2[t] = w2[(t & 31) * 384 + (t >> 5)];   // 32 oc, K=384
    if (t < 49152) wT3[t] = w3[(t & 63) * 768 + (t >> 6)];   // 64 oc, K=768
}

// ---------------- conv1: x(512,1,72,64) -> out1c(nl,16,36,32) --------------
__global__ __launch_bounds__(384) void conv1_k(
    const float* __restrict__ x, const float* __restrict__ w,
    const float* __restrict__ bias, const float* __restrict__ g,
    const float* __restrict__ bt, const float* __restrict__ m,
    const float* __restrict__ v, float* __restrict__ out1,
    int nb0)
{
    __shared__ float4 xs4[1152];                 // 72*64 floats = 18.4 KB
    const int nl = blockIdx.x, oc = blockIdx.y, tid = threadIdx.x;
    const float4* src = (const float4*)(x + (size_t)(nb0 + nl) * 4608);
    for (int i = tid; i < 1152; i += 384) xs4[i] = src[i];
    __syncthreads();
    const float* xs = (const float*)xs4;
    const float* wp = w + oc * 24;               // uniform -> s_load
    const float b = bias[oc];
    const float scale = g[oc] / sqrtf(v[oc] + BN_EPS);
    const float mean = m[oc], beta = bt[oc];

    for (int pos = tid; pos < 1152; pos += 384) { // 3 full iterations
        int ph = pos >> 5, pw = pos & 31;
        int y0 = 2 * ph - 2, x0 = 2 * pw - 1;
        float p[7][5];
#pragma unroll
        for (int dy = 0; dy < 7; ++dy) {
            int iy = y0 + dy;
            bool yok = (iy >= 0) & (iy < 72);
#pragma unroll
            for (int dx = 0; dx < 5; ++dx) {
                int ix = x0 + dx;
                p[dy][dx] = (yok & (ix >= 0) & (ix < 64)) ? xs[iy * 64 + ix] : 0.f;
            }
        }
        float mx = -3.4e38f;
#pragma unroll
        for (int py = 0; py < 2; ++py)
#pragma unroll
            for (int px = 0; px < 2; ++px) {
                float a = 0.f;
#pragma unroll
                for (int kh = 0; kh < 6; ++kh)
#pragma unroll
                    for (int kw = 0; kw < 4; ++kw)
                        a = fmaf(p[py + kh][px + kw], wp[kh * 4 + kw], a);
                float val = fmaxf(a + b, 0.f);
                val = (val - mean) * scale + beta;
                mx = fmaxf(mx, val);
            }
        out1[((nl * 16 + oc) * 36 + ph) * 32 + pw] = mx;
    }
}

// ---------------- conv2: out1c(nl,16,36,32) -> out2c(nl,32,18,16) ----------
// grid (Bc, 4): chunk-batch x 8-oc-group. Input staged in 2 passes of 8 ic.
__global__ __launch_bounds__(320) void conv2_k(
    const float* __restrict__ in, const float* __restrict__ wT,
    const float* __restrict__ bias, const float* __restrict__ g,
    const float* __restrict__ bt, const float* __restrict__ m,
    const float* __restrict__ v, float* __restrict__ out)
{
    __shared__ float4 s4[2304];                  // 8 ic * 36*32 = 36.9 KB
    float* lds = (float*)s4;
    const int nl = blockIdx.x, ocb = blockIdx.y * 8, tid = threadIdx.x;
    const int pos = tid;                         // < 288 active for compute
    const int ph = pos >> 4, pw = pos & 15;
    const int y0 = 2 * ph - 2, x0 = 2 * pw - 1;

    float acc[2][2][8];
#pragma unroll
    for (int py = 0; py < 2; ++py)
#pragma unroll
        for (int px = 0; px < 2; ++px)
#pragma unroll
            for (int j = 0; j < 8; ++j) acc[py][px][j] = 0.f;

    for (int pass = 0; pass < 2; ++pass) {
        __syncthreads();                         // previous-pass readers done
        const float4* src = (const float4*)(in + (size_t)nl * 18432 + pass * 9216);
        for (int i = tid; i < 2304; i += 320) s4[i] = src[i];
        __syncthreads();
        if (pos < 288) {
            for (int icl = 0; icl < 8; ++icl) {
                const float* base = lds + icl * 1152;
                const int ic = pass * 8 + icl;
#pragma unroll
                for (int ky = 0; ky < 6; ++ky) {
                    int Y = y0 + ky;
#pragma unroll
                    for (int kx = 0; kx < 4; ++kx) {
                        int X = x0 + kx;
                        float iv[2][2];
#pragma unroll
                        for (int py = 0; py < 2; ++py) {
                            int iy = Y + py;
                            bool yok = (iy >= 0) & (iy < 36);
#pragma unroll
                            for (int px = 0; px < 2; ++px) {
                                int ix = X + px;
                                iv[py][px] = (yok & (ix >= 0) & (ix < 32))
                                                 ? base[iy * 32 + ix] : 0.f;
                            }
                        }
                        const float* wp = wT + ((ic * 6 + ky) * 4 + kx) * 32 + ocb;
#pragma unroll
                        for (int j = 0; j < 8; ++j) {
                            float wv = wp[j];    // uniform -> SGPR
#pragma unroll
                            for (int py = 0; py < 2; ++py)
#pragma unroll
                                for (int px = 0; px < 2; ++px)
                                    acc[py][px][j] = fmaf(iv[py][px], wv, acc[py][px][j]);
                        }
                    }
                }
            }
        }
    }
    if (pos < 288) {
#pragma unroll
        for (int j = 0; j < 8; ++j) {
            int oc = ocb + j;
            float b = bias[oc];
            float scale = g[oc] / sqrtf(v[oc] + BN_EPS);
            float mean = m[oc], beta = bt[oc];
            float mx = -3.4e38f;
#pragma unroll
            for (int py = 0; py < 2; ++py)
#pragma unroll
                for (int px = 0; px < 2; ++px) {
                    float val = fmaxf(acc[py][px][j] + b, 0.f);
                    val = (val - mean) * scale + beta;
                    mx = fmaxf(mx, val);
                }
            out[((nl * 32 + oc) * 18 + ph) * 16 + pw] = mx;
        }
    }
}

// ---------------- conv3: out2c(nl,32,18,16) -> out3 GLOBAL (512,1536) ------
// grid (Bc, 4): chunk-batch x 16-oc-group. pool (3,4) via LDS scratch.
__global__ __launch_bounds__(320) void conv3_k(
    const float* __restrict__ in, const float* __restrict__ wT,
    const float* __restrict__ bias, const float* __restrict__ g,
    const float* __restrict__ bt, const float* __restrict__ m,
    const float* __restrict__ v, float* __restrict__ out,
    int nb0)
{
    __shared__ float4 s4[2304];                  // 32 ic * 18*16 = 36.9 KB
    __shared__ float sc[4608];                   // 288 pixels * 16 oc = 18.4 KB
    float* lds = (float*)s4;
    const int nl = blockIdx.x, ocb = blockIdx.y * 16, tid = threadIdx.x;
    const float4* src = (const float4*)(in + (size_t)nl * 9216);
    for (int i = tid; i < 2304; i += 320) s4[i] = src[i];
    __syncthreads();

    const int cp = tid;                          // conv pixel, < 288 active
    if (cp < 288) {
        const int oh = cp >> 4, ow = cp & 15;
        float acc[16];
#pragma unroll
        for (int j = 0; j < 16; ++j) acc[j] = 0.f;
        for (int ic = 0; ic < 32; ++ic) {
            const float* base = lds + ic * 288;
#pragma unroll
            for (int ky = 0; ky < 6; ++ky) {
                int iy = oh + ky - 2;
                bool yok = (iy >= 0) & (iy < 18);
#pragma unroll
                for (int kx = 0; kx < 4; ++kx) {
                    int ix = ow + kx - 1;
                    float iv = (yok & (ix >= 0) & (ix < 16)) ? base[iy * 16 + ix] : 0.f;
                    const float* wp = wT + ((ic * 6 + ky) * 4 + kx) * 64 + ocb;
#pragma unroll
                    for (int j = 0; j < 16; ++j)
                        acc[j] = fmaf(iv, wp[j], acc[j]);
                }
            }
        }
#pragma unroll
        for (int j = 0; j < 16; ++j) {
            int oc = ocb + j;
            float val = fmaxf(acc[j] + bias[oc], 0.f);
            val = (val - m[oc]) * (g[oc] / sqrtf(v[oc] + BN_EPS)) + bt[oc];
            sc[cp * 16 + j] = val;
        }
    }
    __syncthreads();
    for (int o = tid; o < 384; o += 320) {       // 24 pooled pos * 16 oc
        int j = o & 15, pp = o >> 4;
        int pph = pp >> 2, ppw = pp & 3;
        float mx = -3.4e38f;
#pragma unroll
        for (int dy = 0; dy < 3; ++dy)
#pragma unroll
            for (int dx = 0; dx < 4; ++dx)
                mx = fmaxf(mx, sc[((pph * 3 + dy) * 16 + (ppw * 4 + dx)) * 16 + j]);
        // flatten: f = oc*24 + pph*4 + ppw
        out[(size_t)(nb0 + nl) * 1536 + (ocb + j) * 24 + pp] = mx;
    }
}

// ---------------- fc: out(512,N) = BN(relu(A(512,K) @ W(N,K)^T + b)) -------
__global__ __launch_bounds__(256) void fc_k(
    const float* __restrict__ A, const float* __restrict__ W,
    const float* __restrict__ bias, const float* __restrict__ g,
    const float* __restrict__ bt, const float* __restrict__ m,
    const float* __restrict__ v, float* __restrict__ out, int K, int N)
{
    __shared__ float As[64][17];
    __shared__ float Ws[64][17];
    const int tid = threadIdx.x;
    const int tx = tid & 15, ty = tid >> 4;
    const int r0 = blockIdx.y * 64, c0 = blockIdx.x * 64;
    const int ld_r = tid >> 2, ld_c = (tid & 3) * 4;
    float acc[4][4];
#pragma unroll
    for (int i = 0; i < 4; ++i)
#pragma unroll
        for (int j = 0; j < 4; ++j) acc[i][j] = 0.f;

    for (int kb = 0; kb < K; kb += 16) {
        float4 av = *(const float4*)(A + (size_t)(r0 + ld_r) * K + kb + ld_c);
        float4 wv = *(const float4*)(W + (size_t)(c0 + ld_r) * K + kb + ld_c);
        __syncthreads();
        As[ld_r][ld_c + 0] = av.x; As[ld_r][ld_c + 1] = av.y;
        As[ld_r][ld_c + 2] = av.z; As[ld_r][ld_c + 3] = av.w;
        Ws[ld_r][ld_c + 0] = wv.x; Ws[ld_r][ld_c + 1] = wv.y;
        Ws[ld_r][ld_c + 2] = wv.z; Ws[ld_r][ld_c + 3] = wv.w;
        __syncthreads();
#pragma unroll
        for (int kk = 0; kk < 16; ++kk) {
            float a[4], w[4];
#pragma unroll
            for (int i = 0; i < 4; ++i) { a[i] = As[ty * 4 + i][kk]; w[i] = Ws[tx * 4 + i][kk]; }
#pragma unroll
            for (int i = 0; i < 4; ++i)
#pragma unroll
                for (int j = 0; j < 4; ++j) acc[i][j] = fmaf(a[i], w[j], acc[i][j]);
        }
    }
#pragma unroll
    for (int j = 0; j < 4; ++j) {
        int c = c0 + tx * 4 + j;
        float b = bias[c], scale = g[c] / sqrtf(v[c] + BN_EPS);
        float mean = m[c], beta = bt[c];
#pragma unroll
        for (int i = 0; i < 4; ++i) {
            int r = r0 + ty * 4 + i;
            float val = fmaxf(acc[i][j] + b, 0.f);
            out[(size_t)r * N + c] = (val - mean) * scale + beta;
        }
    }
}

// ---------------- row L2-normalize; also emit sq = sum(E^2) ----------------
__global__ __launch_bounds__(128) void norm_k(const float* __restrict__ f3,
                                              float* __restrict__ E,
                                              float* __restrict__ sq)
{
    __shared__ float red[2];
    const int row = blockIdx.x, tid = threadIdx.x;
    float vv = f3[row * 128 + tid];
    float s = vv * vv;
#pragma unroll
    for (int off = 32; off >= 1; off >>= 1) s += __shfl_down(s, off, 64);
    if ((tid & 63) == 0) red[tid >> 6] = s;
    __syncthreads();
    float total = red[0] + red[1];
    float nn = fmaxf(sqrtf(total), 1e-12f);
    E[row * 128 + tid] = vv / nn;
    if (tid == 0) sq[row] = total / (nn * nn);
}

// ---------------- pairwise distance + global max (uint atomicMax) ----------
__global__ __launch_bounds__(256) void dist_k(const float* __restrict__ E,
                                              const float* __restrict__ sq,
                                              float* __restrict__ D,
                                              unsigned* __restrict__ mxslot)
{
    __shared__ __align__(16) float Ei[16 * 132];
    __shared__ __align__(16) float Ej[16 * 132];
    __shared__ float red[256];
    const int tid = threadIdx.x;
    const int bi = blockIdx.y * 16, bj = blockIdx.x * 16;
    {
        int lr = tid >> 4, lc = (tid & 15) * 8;
        float4 a0 = *(const float4*)(E + (bi + lr) * 128 + lc);
        float4 a1 = *(const float4*)(E + (bi + lr) * 128 + lc + 4);
        *(float4*)(Ei + lr * 132 + lc) = a0;
        *(float4*)(Ei + lr * 132 + lc + 4) = a1;
        float4 b0 = *(const float4*)(E + (bj + lr) * 128 + lc);
        float4 b1 = *(const float4*)(E + (bj + lr) * 128 + lc + 4);
        *(float4*)(Ej + lr * 132 + lc) = b0;
        *(float4*)(Ej + lr * 132 + lc + 4) = b1;
    }
    __syncthreads();
    const int tx = tid & 15, ty = tid >> 4;
    float dot = 0.f;
#pragma unroll 4
    for (int k = 0; k < 128; k += 4) {
        float4 a = *(const float4*)(Ei + ty * 132 + k);
        float4 b = *(const float4*)(Ej + tx * 132 + k);
        dot = fmaf(a.x, b.x, dot); dot = fmaf(a.y, b.y, dot);
        dot = fmaf(a.z, b.z, dot); dot = fmaf(a.w, b.w, dot);
    }
    int i = bi + ty, j = bj + tx;
    float d2 = sq[i] + sq[j] - 2.f * dot;
    float dist = sqrtf(fmaxf(d2, 1e-12f));
    dist = (d2 > 0.f) ? dist : 0.f;
    if (i == j) dist = 0.f;                      // exact-0 diag (matches ref)
    D[i * 512 + j] = dist;
    red[tid] = dist;
    __syncthreads();
    for (int s2 = 128; s2 > 0; s2 >>= 1) {
        if (tid < s2) red[tid] = fmaxf(red[tid], red[tid + s2]);
        __syncthreads();
    }
    if (tid == 0) atomicMax(mxslot, __float_as_uint(red[0])); // dist >= 0
}

__global__ __launch_bounds__(256) void scale_k(float* __restrict__ D,
                                               const unsigned* __restrict__ mxslot)
{
    int idx = blockIdx.x * 256 + threadIdx.x;
    float M = __uint_as_float(*mxslot);
    D[idx] = D[idx] / M;
}

// ---------------------------------------------------------------------------
extern "C" void kernel_launch(void* const* d_in, const int* in_sizes, int n_in,
                              void* d_out, int out_size, void* d_ws, size_t ws_size,
                              hipStream_t stream)
{
    (void)in_sizes; (void)n_in; (void)out_size;
    const float* x   = (const float*)d_in[0];
    const float* c1w = (const float*)d_in[1];
    const float* c1b = (const float*)d_in[2];
    const float* g1  = (const float*)d_in[3];
    const float* b1  = (const float*)d_in[4];
    const float* m1  = (const float*)d_in[5];
    const float* v1  = (const float*)d_in[6];
    const float* c2w = (const float*)d_in[7];
    const float* c2b = (const float*)d_in[8];
    const float* g2  = (const float*)d_in[9];
    const float* b2  = (const float*)d_in[10];
    const float* m2  = (const float*)d_in[11];
    const float* v2  = (const float*)d_in[12];
    const float* c3w = (const float*)d_in[13];
    const float* c3b = (const float*)d_in[14];
    const float* g3  = (const float*)d_in[15];
    const float* b3  = (const float*)d_in[16];
    const float* m3  = (const float*)d_in[17];
    const float* v3  = (const float*)d_in[18];
    const float* f1w = (const float*)d_in[19];
    const float* f1b = (const float*)d_in[20];
    const float* gf1 = (const float*)d_in[21];
    const float* bf1 = (const float*)d_in[22];
    const float* mf1 = (const float*)d_in[23];
    const float* vf1 = (const float*)d_in[24];
    const float* f2w = (const float*)d_in[25];
    const float* f2b = (const float*)d_in[26];
    const float* gf2 = (const float*)d_in[27];
    const float* bf2 = (const float*)d_in[28];
    const float* mf2 = (const float*)d_in[29];
    const float* vf2 = (const float*)d_in[30];
    const float* f3w = (const float*)d_in[31];
    const float* f3b = (const float*)d_in[32];
    const float* gf3 = (const float*)d_in[33];
    const float* bf3 = (const float*)d_in[34];
    const float* mf3 = (const float*)d_in[35];
    const float* vf3 = (const float*)d_in[36];

    float* ws = (float*)d_ws;
    // ---- persistent region (floats): ~5.5 MB ------------------------------
    float* out3 = ws + 0;            // 512*1536 = 786432
    float* f1   = ws + 786432;       // 512*512  = 262144
    float* f2   = ws + 1048576;      // 512*256  = 131072
    float* f3   = ws + 1179648;      // 512*128  = 65536
    float* E    = ws + 1245184;      // 512*128  = 65536
    float* sq   = ws + 1310720;      // 512
    unsigned* mx = (unsigned*)(ws + 1311232);
    float* wT2  = ws + 1311296;      // 12288
    float* wT3  = ws + 1323584;      // 49152
    const size_t CH0 = 1372736;      // chunk buffers start

    // ---- batch-chunk size from ws_size (deterministic every call) ---------
    // per-batch chunk floats: out1 = 18432, out2 = 9216
    int Bc = 64;                     // cap: peak ~12.6 MB even if ws huge
    while (Bc > 4 && (CH0 + (size_t)Bc * 27648) * 4 > ws_size) Bc >>= 1;
    float* out1c = ws + CH0;                         // Bc*18432 floats
    float* out2c = ws + CH0 + (size_t)Bc * 18432;    // Bc*9216 floats

    float* out = (float*)d_out;

    hipMemsetAsync(mx, 0, 4, stream);
    repack_k<<<192, 256, 0, stream>>>(c2w, c3w, wT2, wT3);
    for (int nb0 = 0; nb0 < 512; nb0 += Bc) {
        conv1_k<<<dim3(Bc, 16), 384, 0, stream>>>(x, c1w, c1b, g1, b1, m1, v1, out1c, nb0);
        conv2_k<<<dim3(Bc, 4), 320, 0, stream>>>(out1c, wT2, c2b, g2, b2, m2, v2, out2c);
        conv3_k<<<dim3(Bc, 4), 320, 0, stream>>>(out2c, wT3, c3b, g3, b3, m3, v3, out3, nb0);
    }
    fc_k<<<dim3(8, 8), 256, 0, stream>>>(out3, f1w, f1b, gf1, bf1, mf1, vf1, f1, 1536, 512);
    fc_k<<<dim3(4, 8), 256, 0, stream>>>(f1, f2w, f2b, gf2, bf2, mf2, vf2, f2, 512, 256);
    fc_k<<<dim3(2, 8), 256, 0, stream>>>(f2, f3w, f3b, gf3, bf3, mf3, vf3, f3, 256, 128);
    norm_k<<<512, 128, 0, stream>>>(f3, E, sq);
    dist_k<<<dim3(32, 32), 256, 0, stream>>>(E, sq, out, mx);
    scale_k<<<1024, 256, 0, stream>>>(out, mx);
}

// Round 5
// 400.861 us; speedup vs baseline: 40.0690x; 5.7250x over previous
//
#include <hip/hip_runtime.h>
#include <math.h>

// ---------------------------------------------------------------------------
// Round 5: conv2/conv3 -> implicit-GEMM MFMA bf16 (16x16x32), padded-HWC
// LDS staging (zero pads via memset => no masks in K-loop), weights repacked
// [tap][oc][ic] bf16 so B-frags are 16B coalesced global loads. Pooling done
// in C-layout registers. conv1 fp32 -> packed bf16 HWC writes. FC/norm/dist
// unchanged from R4 (proven). Chunked ws (adaptive Bc up to 512).
// ---------------------------------------------------------------------------

#define BN_EPS 1e-5f

typedef __attribute__((ext_vector_type(8))) short short8;   // 8 bf16 = 4 VGPR
typedef __attribute__((ext_vector_type(4))) float f32x4;

__device__ __forceinline__ unsigned short f2bf(float f) {
    unsigned u = __float_as_uint(f);
    u += 0x7fffu + ((u >> 16) & 1u);          // round-to-nearest-even
    return (unsigned short)(u >> 16);
}

// ---- weight repack ---------------------------------------------------------
// wT2b[kk=ky*2+kxp][oc 32][k 32] bf16, k=hi*16+ic <-> kx=2*kxp+hi (12288)
// wT3b[kk=ky*4+kx ][oc 64][ic 32] bf16                            (49152)
__global__ __launch_bounds__(256) void repack_k(
    const float* __restrict__ w2, const float* __restrict__ w3,
    unsigned short* __restrict__ wT2b, unsigned short* __restrict__ wT3b)
{
    int t = blockIdx.x * 256 + threadIdx.x;
    if (t < 12288) {
        int k = t & 31, oc = (t >> 5) & 31, kk = t >> 10;
        int ky = kk >> 1, kxp = kk & 1;
        int hi = k >> 4, ic = k & 15;
        int kx = 2 * kxp + hi;
        wT2b[t] = f2bf(w2[((oc * 16 + ic) * 6 + ky) * 4 + kx]);
    }
    if (t < 49152) {
        int ic = t & 31, oc = (t >> 5) & 63, kk = t >> 11;
        int ky = kk >> 2, kx = kk & 3;
        wT3b[t] = f2bf(w3[((oc * 32 + ic) * 6 + ky) * 4 + kx]);
    }
}

// ---- conv1: x(n,1,72,64) fp32 -> out1c padded HWC bf16 [41 rows][36 cols][16 ic]
// conv output grid 36x32 (after 2x2 pool); padded row = ph+2, col = pw+1.
__global__ __launch_bounds__(384) void conv1_k(
    const float* __restrict__ x, const float* __restrict__ w,
    const float* __restrict__ bias, const float* __restrict__ g,
    const float* __restrict__ bt, const float* __restrict__ m,
    const float* __restrict__ v, unsigned short* __restrict__ out1,
    int nb0)
{
    __shared__ __align__(16) float xs[72 * 64];
    __shared__ float bnp[16 * 3];
    const int nl = blockIdx.x, tid = threadIdx.x;
    {
        const float4* src = (const float4*)(x + (size_t)(nb0 + nl) * 4608);
        float4* dst = (float4*)xs;
        for (int i = tid; i < 1152; i += 384) dst[i] = src[i];
    }
    if (tid < 16) {
        float sc = g[tid] * rsqrtf(v[tid] + BN_EPS);
        bnp[tid * 3 + 0] = bias[tid];
        bnp[tid * 3 + 1] = sc;
        bnp[tid * 3 + 2] = bt[tid] - m[tid] * sc;
    }
    __syncthreads();
    unsigned short* ob = out1 + (size_t)nl * 23616;

    for (int pos = tid; pos < 1152; pos += 384) {
        int ph = pos >> 5, pw = pos & 31;
        int y0 = 2 * ph - 2, x0 = 2 * pw - 1;
        float p[7][5];
#pragma unroll
        for (int dy = 0; dy < 7; ++dy) {
            int iy = y0 + dy;
            bool yok = (iy >= 0) & (iy < 72);
#pragma unroll
            for (int dx = 0; dx < 5; ++dx) {
                int ix = x0 + dx;
                p[dy][dx] = (yok & (ix >= 0) & (ix < 64)) ? xs[iy * 64 + ix] : 0.f;
            }
        }
        unsigned short us[16];
#pragma unroll
        for (int oc = 0; oc < 16; ++oc) {
            const float* wp = w + oc * 24;        // uniform -> s_load
            float mxa = -3.4e38f;
#pragma unroll
            for (int py = 0; py < 2; ++py)
#pragma unroll
                for (int px = 0; px < 2; ++px) {
                    float a = 0.f;
#pragma unroll
                    for (int kh = 0; kh < 6; ++kh)
#pragma unroll
                        for (int kw = 0; kw < 4; ++kw)
                            a = fmaf(p[py + kh][px + kw], wp[kh * 4 + kw], a);
                    mxa = fmaxf(mxa, a);
                }
            // BN/relu monotone (scale>0) -> apply after pool-max
            float val = fmaxf(mxa + bnp[oc * 3], 0.f) * bnp[oc * 3 + 1] + bnp[oc * 3 + 2];
            us[oc] = f2bf(val);
        }
        unsigned rr[8];
#pragma unroll
        for (int i = 0; i < 8; ++i)
            rr[i] = (unsigned)us[2 * i] | ((unsigned)us[2 * i + 1] << 16);
        uint4* dst = (uint4*)(ob + ((size_t)(ph + 2) * 36 + (pw + 1)) * 16);
        uint4 w0; w0.x = rr[0]; w0.y = rr[1]; w0.z = rr[2]; w0.w = rr[3];
        uint4 w1; w1.x = rr[4]; w1.y = rr[5]; w1.z = rr[6]; w1.w = rr[7];
        dst[0] = w0; dst[1] = w1;
    }
}

// ---- conv2 (MFMA): out1c padded HWC [41][36][16] -> out2c padded HWC [24][20][32]
// GEMM: M=1152 conv pos, N=32 oc, K=384 (12 taps x K32). Block = 1 batch, 4 waves.
__global__ __launch_bounds__(256) void conv2_m(
    const unsigned short* __restrict__ in, const unsigned short* __restrict__ wT,
    const float* __restrict__ bias, const float* __restrict__ g,
    const float* __restrict__ bt, const float* __restrict__ m,
    const float* __restrict__ v, unsigned short* __restrict__ out)
{
    __shared__ __align__(16) unsigned short in_s[41 * 36 * 16];   // 47232 B
    const int tid = threadIdx.x, nl = blockIdx.x;
    {
        const uint4* src = (const uint4*)(in + (size_t)nl * 23616);
        uint4* dst = (uint4*)in_s;
        for (int i = tid; i < 2952; i += 256) dst[i] = src[i];
    }
    const int lane = tid & 63, wave = tid >> 6;
    const int n = lane & 15, q = lane >> 4;
    float bnb[2], bns[2], bnm[2];
#pragma unroll
    for (int nt = 0; nt < 2; ++nt) {
        int oc = nt * 16 + n;
        float sc = g[oc] * rsqrtf(v[oc] + BN_EPS);
        bnb[nt] = bias[oc]; bns[nt] = sc; bnm[nt] = bt[oc] - m[oc] * sc;
    }
    __syncthreads();
    unsigned short* ob = out + (size_t)nl * 15360;

    for (int pass = 0; pass < 3; ++pass) {
        f32x4 acc[3][2][2];                       // [pair j][row a/b][nt]
#pragma unroll
        for (int j = 0; j < 3; ++j)
#pragma unroll
            for (int ab = 0; ab < 2; ++ab)
#pragma unroll
                for (int nt = 0; nt < 2; ++nt)
                    acc[j][ab][nt] = (f32x4){0.f, 0.f, 0.f, 0.f};

#pragma unroll
        for (int ky = 0; ky < 6; ++ky)
#pragma unroll
            for (int kxp = 0; kxp < 2; ++kxp) {
                int kk = ky * 2 + kxp;
                short8 bfr[2];
#pragma unroll
                for (int nt = 0; nt < 2; ++nt)
                    bfr[nt] = *(const short8*)(wT + (((size_t)kk * 32 + nt * 16 + n) * 32 + q * 8));
#pragma unroll
                for (int j = 0; j < 3; ++j) {
                    int pp = wave + 4 * (pass * 3 + j);
                    int ph = pp >> 1, half = pp & 1;
                    int col = half * 16 + n + 2 * kxp;     // A row m = lane&15
#pragma unroll
                    for (int ab = 0; ab < 2; ++ab) {
                        int row = 2 * ph + ab + ky;
                        short8 afr = *(const short8*)(in_s + (((size_t)row * 36 + col) * 16 + q * 8));
                        acc[j][ab][0] = __builtin_amdgcn_mfma_f32_16x16x32_bf16(afr, bfr[0], acc[j][ab][0], 0, 0, 0);
                        acc[j][ab][1] = __builtin_amdgcn_mfma_f32_16x16x32_bf16(afr, bfr[1], acc[j][ab][1], 0, 0, 0);
                    }
                }
            }
        // epilogue: 2x2 pool in regs (D: oc=lane&15, pos=q*4+reg), BN after (sc>0)
#pragma unroll
        for (int j = 0; j < 3; ++j) {
            int pp = wave + 4 * (pass * 3 + j);
            int ph = pp >> 1, half = pp & 1;
            int pw0 = half * 8 + q * 2;
#pragma unroll
            for (int nt = 0; nt < 2; ++nt) {
                int oc = nt * 16 + n;
                float p0 = fmaxf(fmaxf(acc[j][0][nt][0], acc[j][0][nt][1]),
                                 fmaxf(acc[j][1][nt][0], acc[j][1][nt][1]));
                float p1 = fmaxf(fmaxf(acc[j][0][nt][2], acc[j][0][nt][3]),
                                 fmaxf(acc[j][1][nt][2], acc[j][1][nt][3]));
                p0 = fmaxf(p0 + bnb[nt], 0.f) * bns[nt] + bnm[nt];
                p1 = fmaxf(p1 + bnb[nt], 0.f) * bns[nt] + bnm[nt];
                ob[((size_t)(ph + 2) * 20 + (pw0 + 1)) * 32 + oc] = f2bf(p0);
                ob[((size_t)(ph + 2) * 20 + (pw0 + 2)) * 32 + oc] = f2bf(p1);
            }
        }
    }
}

// ---- conv3 (MFMA): out2c padded HWC [24][20][32] -> out3 flat (512,1536) fp32
// GEMM: M=288 pos (18 row-tiles of 16), N=64 oc, K=768 (24 taps x K32).
// Block = 1 batch, 6 waves; wave = pool-row pr; pool 3x4 entirely in regs.
__global__ __launch_bounds__(384) void conv3_m(
    const unsigned short* __restrict__ in, const unsigned short* __restrict__ wT,
    const float* __restrict__ bias, const float* __restrict__ g,
    const float* __restrict__ bt, const float* __restrict__ m,
    const float* __restrict__ v, float* __restrict__ out3, int nb0)
{
    __shared__ __align__(16) unsigned short in_s[24 * 20 * 32];   // 30720 B
    const int tid = threadIdx.x, nl = blockIdx.x;
    {
        const uint4* src = (const uint4*)(in + (size_t)nl * 15360);
        uint4* dst = (uint4*)in_s;
        for (int i = tid; i < 1920; i += 384) dst[i] = src[i];
    }
    const int lane = tid & 63, pr = tid >> 6;     // pr = pool row 0..5
    const int n = lane & 15, q = lane >> 4;
    float bnb[4], bns[4], bnm[4];
#pragma unroll
    for (int nt = 0; nt < 4; ++nt) {
        int oc = nt * 16 + n;
        float sc = g[oc] * rsqrtf(v[oc] + BN_EPS);
        bnb[nt] = bias[oc]; bns[nt] = sc; bnm[nt] = bt[oc] - m[oc] * sc;
    }
    __syncthreads();

    f32x4 acc[3][4];                              // [conv row r][nt]
#pragma unroll
    for (int r = 0; r < 3; ++r)
#pragma unroll
        for (int nt = 0; nt < 4; ++nt) acc[r][nt] = (f32x4){0.f, 0.f, 0.f, 0.f};

#pragma unroll
    for (int ky = 0; ky < 6; ++ky)
#pragma unroll
        for (int kx = 0; kx < 4; ++kx) {
            int kk = ky * 4 + kx;
            short8 bfr[4];
#pragma unroll
            for (int nt = 0; nt < 4; ++nt)
                bfr[nt] = *(const short8*)(wT + (((size_t)kk * 64 + nt * 16 + n) * 32 + q * 8));
#pragma unroll
            for (int r = 0; r < 3; ++r) {
                int row = 3 * pr + r + ky;
                int col = n + kx;                 // A row m = lane&15 = ow
                short8 afr = *(const short8*)(in_s + (((size_t)row * 20 + col) * 32 + q * 8));
#pragma unroll
                for (int nt = 0; nt < 4; ++nt)
                    acc[r][nt] = __builtin_amdgcn_mfma_f32_16x16x32_bf16(afr, bfr[nt], acc[r][nt], 0, 0, 0);
            }
        }
    // epilogue: pool 3 rows x 4 regs = (3,4) window at (ph=pr, ppw=q)
    size_t ob = (size_t)(nb0 + nl) * 1536;
#pragma unroll
    for (int nt = 0; nt < 4; ++nt) {
        float mx = -3.4e38f;
#pragma unroll
        for (int r = 0; r < 3; ++r)
#pragma unroll
            for (int e = 0; e < 4; ++e) mx = fmaxf(mx, acc[r][nt][e]);
        float val = fmaxf(mx + bnb[nt], 0.f) * bns[nt] + bnm[nt];
        out3[ob + (size_t)(nt * 16 + n) * 24 + pr * 4 + q] = val;
    }
}

// ---- fc: out(512,N) = BN(relu(A(512,K) @ W(N,K)^T + b)) (unchanged, proven)
__global__ __launch_bounds__(256) void fc_k(
    const float* __restrict__ A, const float* __restrict__ W,
    const float* __restrict__ bias, const float* __restrict__ g,
    const float* __restrict__ bt, const float* __restrict__ m,
    const float* __restrict__ v, float* __restrict__ out, int K, int N)
{
    __shared__ float As[64][17];
    __shared__ float Ws[64][17];
    const int tid = threadIdx.x;
    const int tx = tid & 15, ty = tid >> 4;
    const int r0 = blockIdx.y * 64, c0 = blockIdx.x * 64;
    const int ld_r = tid >> 2, ld_c = (tid & 3) * 4;
    float acc[4][4];
#pragma unroll
    for (int i = 0; i < 4; ++i)
#pragma unroll
        for (int j = 0; j < 4; ++j) acc[i][j] = 0.f;

    for (int kb = 0; kb < K; kb += 16) {
        float4 av = *(const float4*)(A + (size_t)(r0 + ld_r) * K + kb + ld_c);
        float4 wv = *(const float4*)(W + (size_t)(c0 + ld_r) * K + kb + ld_c);
        __syncthreads();
        As[ld_r][ld_c + 0] = av.x; As[ld_r][ld_c + 1] = av.y;
        As[ld_r][ld_c + 2] = av.z; As[ld_r][ld_c + 3] = av.w;
        Ws[ld_r][ld_c + 0] = wv.x; Ws[ld_r][ld_c + 1] = wv.y;
        Ws[ld_r][ld_c + 2] = wv.z; Ws[ld_r][ld_c + 3] = wv.w;
        __syncthreads();
#pragma unroll
        for (int kk = 0; kk < 16; ++kk) {
            float a[4], w[4];
#pragma unroll
            for (int i = 0; i < 4; ++i) { a[i] = As[ty * 4 + i][kk]; w[i] = Ws[tx * 4 + i][kk]; }
#pragma unroll
            for (int i = 0; i < 4; ++i)
#pragma unroll
                for (int j = 0; j < 4; ++j) acc[i][j] = fmaf(a[i], w[j], acc[i][j]);
        }
    }
#pragma unroll
    for (int j = 0; j < 4; ++j) {
        int c = c0 + tx * 4 + j;
        float b = bias[c], scale = g[c] / sqrtf(v[c] + BN_EPS);
        float mean = m[c], beta = bt[c];
#pragma unroll
        for (int i = 0; i < 4; ++i) {
            int r = r0 + ty * 4 + i;
            float val = fmaxf(acc[i][j] + b, 0.f);
            out[(size_t)r * N + c] = (val - mean) * scale + beta;
        }
    }
}

// ---- row L2-normalize; emit sq = sum(e^2) ---------------------------------
__global__ __launch_bounds__(128) void norm_k(const float* __restrict__ f3,
                                              float* __restrict__ E,
                                              float* __restrict__ sq)
{
    __shared__ float red[2];
    const int row = blockIdx.x, tid = threadIdx.x;
    float vv = f3[row * 128 + tid];
    float s = vv * vv;
#pragma unroll
    for (int off = 32; off >= 1; off >>= 1) s += __shfl_down(s, off, 64);
    if ((tid & 63) == 0) red[tid >> 6] = s;
    __syncthreads();
    float total = red[0] + red[1];
    float nn = fmaxf(sqrtf(total), 1e-12f);
    E[row * 128 + tid] = vv / nn;
    if (tid == 0) sq[row] = total / (nn * nn);
}

// ---- pairwise distance + global max ---------------------------------------
__global__ __launch_bounds__(256) void dist_k(const float* __restrict__ E,
                                              const float* __restrict__ sq,
                                              float* __restrict__ D,
                                              unsigned* __restrict__ mxslot)
{
    __shared__ __align__(16) float Ei[16 * 132];
    __shared__ __align__(16) float Ej[16 * 132];
    __shared__ float red[256];
    const int tid = threadIdx.x;
    const int bi = blockIdx.y * 16, bj = blockIdx.x * 16;
    {
        int lr = tid >> 4, lc = (tid & 15) * 8;
        float4 a0 = *(const float4*)(E + (bi + lr) * 128 + lc);
        float4 a1 = *(const float4*)(E + (bi + lr) * 128 + lc + 4);
        *(float4*)(Ei + lr * 132 + lc) = a0;
        *(float4*)(Ei + lr * 132 + lc + 4) = a1;
        float4 b0 = *(const float4*)(E + (bj + lr) * 128 + lc);
        float4 b1 = *(const float4*)(E + (bj + lr) * 128 + lc + 4);
        *(float4*)(Ej + lr * 132 + lc) = b0;
        *(float4*)(Ej + lr * 132 + lc + 4) = b1;
    }
    __syncthreads();
    const int tx = tid & 15, ty = tid >> 4;
    float dot = 0.f;
#pragma unroll 4
    for (int k = 0; k < 128; k += 4) {
        float4 a = *(const float4*)(Ei + ty * 132 + k);
        float4 b = *(const float4*)(Ej + tx * 132 + k);
        dot = fmaf(a.x, b.x, dot); dot = fmaf(a.y, b.y, dot);
        dot = fmaf(a.z, b.z, dot); dot = fmaf(a.w, b.w, dot);
    }
    int i = bi + ty, j = bj + tx;
    float d2 = sq[i] + sq[j] - 2.f * dot;
    float dist = sqrtf(fmaxf(d2, 1e-12f));
    dist = (d2 > 0.f) ? dist : 0.f;
    if (i == j) dist = 0.f;
    D[i * 512 + j] = dist;
    red[tid] = dist;
    __syncthreads();
    for (int s2 = 128; s2 > 0; s2 >>= 1) {
        if (tid < s2) red[tid] = fmaxf(red[tid], red[tid + s2]);
        __syncthreads();
    }
    if (tid == 0) atomicMax(mxslot, __float_as_uint(red[0]));
}

__global__ __launch_bounds__(256) void scale_k(float* __restrict__ D,
                                               const unsigned* __restrict__ mxslot)
{
    int idx = blockIdx.x * 256 + threadIdx.x;
    float M = __uint_as_float(*mxslot);
    D[idx] = D[idx] / M;
}

// ---------------------------------------------------------------------------
extern "C" void kernel_launch(void* const* d_in, const int* in_sizes, int n_in,
                              void* d_out, int out_size, void* d_ws, size_t ws_size,
                              hipStream_t stream)
{
    (void)in_sizes; (void)n_in; (void)out_size;
    const float* x   = (const float*)d_in[0];
    const float* c1w = (const float*)d_in[1];
    const float* c1b = (const float*)d_in[2];
    const float* g1  = (const float*)d_in[3];
    const float* b1  = (const float*)d_in[4];
    const float* m1  = (const float*)d_in[5];
    const float* v1  = (const float*)d_in[6];
    const float* c2w = (const float*)d_in[7];
    const float* c2b = (const float*)d_in[8];
    const float* g2  = (const float*)d_in[9];
    const float* b2  = (const float*)d_in[10];
    const float* m2  = (const float*)d_in[11];
    const float* v2  = (const float*)d_in[12];
    const float* c3w = (const float*)d_in[13];
    const float* c3b = (const float*)d_in[14];
    const float* g3  = (const float*)d_in[15];
    const float* b3  = (const float*)d_in[16];
    const float* m3  = (const float*)d_in[17];
    const float* v3  = (const float*)d_in[18];
    const float* f1w = (const float*)d_in[19];
    const float* f1b = (const float*)d_in[20];
    const float* gf1 = (const float*)d_in[21];
    const float* bf1 = (const float*)d_in[22];
    const float* mf1 = (const float*)d_in[23];
    const float* vf1 = (const float*)d_in[24];
    const float* f2w = (const float*)d_in[25];
    const float* f2b = (const float*)d_in[26];
    const float* gf2 = (const float*)d_in[27];
    const float* bf2 = (const float*)d_in[28];
    const float* mf2 = (const float*)d_in[29];
    const float* vf2 = (const float*)d_in[30];
    const float* f3w = (const float*)d_in[31];
    const float* f3b = (const float*)d_in[32];
    const float* gf3 = (const float*)d_in[33];
    const float* bf3 = (const float*)d_in[34];
    const float* mf3 = (const float*)d_in[35];
    const float* vf3 = (const float*)d_in[36];

    float* ws = (float*)d_ws;
    // ---- persistent region (floats): ~5.4 MB ------------------------------
    float* out3 = ws + 0;            // 786432
    float* f1   = ws + 786432;       // 262144
    float* f2   = ws + 1048576;      // 131072
    float* f3   = ws + 1179648;      // 65536
    float* E    = ws + 1245184;      // 65536
    float* sq   = ws + 1310720;      // 512
    unsigned* mx = (unsigned*)(ws + 1311232);
    unsigned short* wT2b = (unsigned short*)(ws + 1311248);  // 12288 ush
    unsigned short* wT3b = (unsigned short*)(ws + 1317392);  // 49152 ush
    const size_t CH0 = 1341968;      // chunk region start (16B aligned)

    // chunk bytes/batch: out1c 41*36*16*2 = 47232, out2c 24*20*32*2 = 30720
    int Bc = 512;
    while (Bc > 4 && (size_t)CH0 * 4 + (size_t)Bc * 77952 > ws_size) Bc >>= 1;
    unsigned short* out1c = (unsigned short*)(ws + CH0);
    unsigned short* out2c = out1c + (size_t)Bc * 23616;

    float* out = (float*)d_out;

    hipMemsetAsync(mx, 0, 4, stream);
    repack_k<<<192, 256, 0, stream>>>(c2w, c3w, wT2b, wT3b);
    for (int nb0 = 0; nb0 < 512; nb0 += Bc) {
        hipMemsetAsync(out1c, 0, (size_t)Bc * 77952, stream);  // zero pads
        conv1_k<<<Bc, 384, 0, stream>>>(x, c1w, c1b, g1, b1, m1, v1, out1c, nb0);
        conv2_m<<<Bc, 256, 0, stream>>>(out1c, wT2b, c2b, g2, b2, m2, v2, out2c);
        conv3_m<<<Bc, 384, 0, stream>>>(out2c, wT3b, c3b, g3, b3, m3, v3, out3, nb0);
    }
    fc_k<<<dim3(8, 8), 256, 0, stream>>>(out3, f1w, f1b, gf1, bf1, mf1, vf1, f1, 1536, 512);
    fc_k<<<dim3(4, 8), 256, 0, stream>>>(f1, f2w, f2b, gf2, bf2, mf2, vf2, f2, 512, 256);
    fc_k<<<dim3(2, 8), 256, 0, stream>>>(f2, f3w, f3b, gf3, bf3, mf3, vf3, f3, 256, 128);
    norm_k<<<512, 128, 0, stream>>>(f3, E, sq);
    dist_k<<<dim3(32, 32), 256, 0, stream>>>(E, sq, out, mx);
    scale_k<<<1024, 256, 0, stream>>>(out, mx);
}

// Round 6
// 269.459 us; speedup vs baseline: 59.6087x; 1.4877x over previous
//
#include <hip/hip_runtime.h>
#include <math.h>

// ---------------------------------------------------------------------------
// Round 6: FC stack -> LDS-free bf16 MFMA (wave = 16x16 C tile, fragments
// loaded straight from global in native layout; block = 2x2 waves = 32x32).
// conv3 emits bf16; fc1/fc2 emit bf16 activations; fc3 emits fp32 for
// norm/dist. Chunk memset removed: conv1/conv2 zero their own pad cells.
// ---------------------------------------------------------------------------

#define BN_EPS 1e-5f

typedef __attribute__((ext_vector_type(8))) short short8;   // 8 bf16 = 4 VGPR
typedef __attribute__((ext_vector_type(4))) float f32x4;

__device__ __forceinline__ unsigned short f2bf(float f) {
    unsigned u = __float_as_uint(f);
    u += 0x7fffu + ((u >> 16) & 1u);          // round-to-nearest-even
    return (unsigned short)(u >> 16);
}

// ---- weight repack + fc-weight bf16 cast ----------------------------------
// wT2b[kk=ky*2+kxp][oc 32][k 32] bf16, k=hi*16+ic <-> kx=2*kxp+hi (12288)
// wT3b[kk=ky*4+kx ][oc 64][ic 32] bf16                            (49152)
__global__ __launch_bounds__(256) void repack_k(
    const float* __restrict__ w2, const float* __restrict__ w3,
    const float* __restrict__ fw1, const float* __restrict__ fw2,
    const float* __restrict__ fw3,
    unsigned short* __restrict__ wT2b, unsigned short* __restrict__ wT3b,
    unsigned short* __restrict__ fw1b, unsigned short* __restrict__ fw2b,
    unsigned short* __restrict__ fw3b)
{
    int t = blockIdx.x * 256 + threadIdx.x;
    if (t < 12288) {
        int k = t & 31, oc = (t >> 5) & 31, kk = t >> 10;
        int ky = kk >> 1, kxp = kk & 1;
        int hi = k >> 4, ic = k & 15;
        int kx = 2 * kxp + hi;
        wT2b[t] = f2bf(w2[((oc * 16 + ic) * 6 + ky) * 4 + kx]);
    }
    if (t < 49152) {
        int ic = t & 31, oc = (t >> 5) & 63, kk = t >> 11;
        int ky = kk >> 2, kx = kk & 3;
        wT3b[t] = f2bf(w3[((oc * 32 + ic) * 6 + ky) * 4 + kx]);
    }
    if (t < 786432) fw1b[t] = f2bf(fw1[t]);
    if (t < 131072) fw2b[t] = f2bf(fw2[t]);
    if (t < 32768)  fw3b[t] = f2bf(fw3[t]);
}

// ---- conv1: x(n,1,72,64) fp32 -> out1c padded HWC bf16 [41][36][16] -------
__global__ __launch_bounds__(384) void conv1_k(
    const float* __restrict__ x, const float* __restrict__ w,
    const float* __restrict__ bias, const float* __restrict__ g,
    const float* __restrict__ bt, const float* __restrict__ m,
    const float* __restrict__ v, unsigned short* __restrict__ out1,
    int nb0)
{
    __shared__ __align__(16) float xs[72 * 64];
    __shared__ float bnp[16 * 3];
    const int nl = blockIdx.x, tid = threadIdx.x;
    {
        const float4* src = (const float4*)(x + (size_t)(nb0 + nl) * 4608);
        float4* dst = (float4*)xs;
        for (int i = tid; i < 1152; i += 384) dst[i] = src[i];
    }
    if (tid < 16) {
        float sc = g[tid] * rsqrtf(v[tid] + BN_EPS);
        bnp[tid * 3 + 0] = bias[tid];
        bnp[tid * 3 + 1] = sc;
        bnp[tid * 3 + 2] = bt[tid] - m[tid] * sc;
    }
    unsigned short* ob = out1 + (size_t)nl * 23616;
    // zero pads: rows {0,1,38,39,40} x 36 cols + rows 2..37 x cols {0,33,34,35}
    {
        uint4 z; z.x = z.y = z.z = z.w = 0u;
        for (int pc = tid; pc < 324; pc += 384) {
            int row, colc;
            if (pc < 180) { row = pc / 36; colc = pc % 36; if (row >= 2) row += 36; }
            else { int pz = pc - 180; row = 2 + (pz >> 2); colc = (pz & 3) ? 32 + (pz & 3) : 0; }
            uint4* d = (uint4*)(ob + ((size_t)row * 36 + colc) * 16);
            d[0] = z; d[1] = z;
        }
    }
    __syncthreads();

    for (int pos = tid; pos < 1152; pos += 384) {
        int ph = pos >> 5, pw = pos & 31;
        int y0 = 2 * ph - 2, x0 = 2 * pw - 1;
        float p[7][5];
#pragma unroll
        for (int dy = 0; dy < 7; ++dy) {
            int iy = y0 + dy;
            bool yok = (iy >= 0) & (iy < 72);
#pragma unroll
            for (int dx = 0; dx < 5; ++dx) {
                int ix = x0 + dx;
                p[dy][dx] = (yok & (ix >= 0) & (ix < 64)) ? xs[iy * 64 + ix] : 0.f;
            }
        }
        unsigned short us[16];
#pragma unroll
        for (int oc = 0; oc < 16; ++oc) {
            const float* wp = w + oc * 24;        // uniform -> s_load
            float mxa = -3.4e38f;
#pragma unroll
            for (int py = 0; py < 2; ++py)
#pragma unroll
                for (int px = 0; px < 2; ++px) {
                    float a = 0.f;
#pragma unroll
                    for (int kh = 0; kh < 6; ++kh)
#pragma unroll
                        for (int kw = 0; kw < 4; ++kw)
                            a = fmaf(p[py + kh][px + kw], wp[kh * 4 + kw], a);
                    mxa = fmaxf(mxa, a);
                }
            float val = fmaxf(mxa + bnp[oc * 3], 0.f) * bnp[oc * 3 + 1] + bnp[oc * 3 + 2];
            us[oc] = f2bf(val);
        }
        unsigned rr[8];
#pragma unroll
        for (int i = 0; i < 8; ++i)
            rr[i] = (unsigned)us[2 * i] | ((unsigned)us[2 * i + 1] << 16);
        uint4* dst = (uint4*)(ob + ((size_t)(ph + 2) * 36 + (pw + 1)) * 16);
        uint4 w0; w0.x = rr[0]; w0.y = rr[1]; w0.z = rr[2]; w0.w = rr[3];
        uint4 w1; w1.x = rr[4]; w1.y = rr[5]; w1.z = rr[6]; w1.w = rr[7];
        dst[0] = w0; dst[1] = w1;
    }
}

// ---- conv2 (MFMA): out1c [41][36][16] -> out2c padded HWC [24][20][32] ----
__global__ __launch_bounds__(256) void conv2_m(
    const unsigned short* __restrict__ in, const unsigned short* __restrict__ wT,
    const float* __restrict__ bias, const float* __restrict__ g,
    const float* __restrict__ bt, const float* __restrict__ m,
    const float* __restrict__ v, unsigned short* __restrict__ out)
{
    __shared__ __align__(16) unsigned short in_s[41 * 36 * 16];   // 47232 B
    const int tid = threadIdx.x, nl = blockIdx.x;
    {
        const uint4* src = (const uint4*)(in + (size_t)nl * 23616);
        uint4* dst = (uint4*)in_s;
        for (int i = tid; i < 2952; i += 256) dst[i] = src[i];
    }
    unsigned short* ob = out + (size_t)nl * 15360;
    // zero pads: rows {0,1,20,21,22,23} x 20 cols + rows 2..19 x cols {0,17,18,19}
    {
        uint4 z; z.x = z.y = z.z = z.w = 0u;
        for (int pc = tid; pc < 192; pc += 256) {
            int row, colc;
            if (pc < 120) { row = pc / 20; colc = pc % 20; if (row >= 2) row += 18; }
            else { int pz = pc - 120; row = 2 + (pz >> 2); colc = (pz & 3) ? 16 + (pz & 3) : 0; }
            uint4* d = (uint4*)(ob + ((size_t)row * 20 + colc) * 32);
            d[0] = z; d[1] = z; d[2] = z; d[3] = z;
        }
    }
    const int lane = tid & 63, wave = tid >> 6;
    const int n = lane & 15, q = lane >> 4;
    float bnb[2], bns[2], bnm[2];
#pragma unroll
    for (int nt = 0; nt < 2; ++nt) {
        int oc = nt * 16 + n;
        float sc = g[oc] * rsqrtf(v[oc] + BN_EPS);
        bnb[nt] = bias[oc]; bns[nt] = sc; bnm[nt] = bt[oc] - m[oc] * sc;
    }
    __syncthreads();

    for (int pass = 0; pass < 3; ++pass) {
        f32x4 acc[3][2][2];
#pragma unroll
        for (int j = 0; j < 3; ++j)
#pragma unroll
            for (int ab = 0; ab < 2; ++ab)
#pragma unroll
                for (int nt = 0; nt < 2; ++nt)
                    acc[j][ab][nt] = (f32x4){0.f, 0.f, 0.f, 0.f};

#pragma unroll
        for (int ky = 0; ky < 6; ++ky)
#pragma unroll
            for (int kxp = 0; kxp < 2; ++kxp) {
                int kk = ky * 2 + kxp;
                short8 bfr[2];
#pragma unroll
                for (int nt = 0; nt < 2; ++nt)
                    bfr[nt] = *(const short8*)(wT + (((size_t)kk * 32 + nt * 16 + n) * 32 + q * 8));
#pragma unroll
                for (int j = 0; j < 3; ++j) {
                    int pp = wave + 4 * (pass * 3 + j);
                    int ph = pp >> 1, half = pp & 1;
                    int col = half * 16 + n + 2 * kxp;
#pragma unroll
                    for (int ab = 0; ab < 2; ++ab) {
                        int row = 2 * ph + ab + ky;
                        short8 afr = *(const short8*)(in_s + (((size_t)row * 36 + col) * 16 + q * 8));
                        acc[j][ab][0] = __builtin_amdgcn_mfma_f32_16x16x32_bf16(afr, bfr[0], acc[j][ab][0], 0, 0, 0);
                        acc[j][ab][1] = __builtin_amdgcn_mfma_f32_16x16x32_bf16(afr, bfr[1], acc[j][ab][1], 0, 0, 0);
                    }
                }
            }
#pragma unroll
        for (int j = 0; j < 3; ++j) {
            int pp = wave + 4 * (pass * 3 + j);
            int ph = pp >> 1, half = pp & 1;
            int pw0 = half * 8 + q * 2;
#pragma unroll
            for (int nt = 0; nt < 2; ++nt) {
                int oc = nt * 16 + n;
                float p0 = fmaxf(fmaxf(acc[j][0][nt][0], acc[j][0][nt][1]),
                                 fmaxf(acc[j][1][nt][0], acc[j][1][nt][1]));
                float p1 = fmaxf(fmaxf(acc[j][0][nt][2], acc[j][0][nt][3]),
                                 fmaxf(acc[j][1][nt][2], acc[j][1][nt][3]));
                p0 = fmaxf(p0 + bnb[nt], 0.f) * bns[nt] + bnm[nt];
                p1 = fmaxf(p1 + bnb[nt], 0.f) * bns[nt] + bnm[nt];
                ob[((size_t)(ph + 2) * 20 + (pw0 + 1)) * 32 + oc] = f2bf(p0);
                ob[((size_t)(ph + 2) * 20 + (pw0 + 2)) * 32 + oc] = f2bf(p1);
            }
        }
    }
}

// ---- conv3 (MFMA): out2c [24][20][32] -> out3 flat (512,1536) bf16 --------
__global__ __launch_bounds__(384) void conv3_m(
    const unsigned short* __restrict__ in, const unsigned short* __restrict__ wT,
    const float* __restrict__ bias, const float* __restrict__ g,
    const float* __restrict__ bt, const float* __restrict__ m,
    const float* __restrict__ v, unsigned short* __restrict__ out3, int nb0)
{
    __shared__ __align__(16) unsigned short in_s[24 * 20 * 32];   // 30720 B
    const int tid = threadIdx.x, nl = blockIdx.x;
    {
        const uint4* src = (const uint4*)(in + (size_t)nl * 15360);
        uint4* dst = (uint4*)in_s;
        for (int i = tid; i < 1920; i += 384) dst[i] = src[i];
    }
    const int lane = tid & 63, pr = tid >> 6;
    const int n = lane & 15, q = lane >> 4;
    float bnb[4], bns[4], bnm[4];
#pragma unroll
    for (int nt = 0; nt < 4; ++nt) {
        int oc = nt * 16 + n;
        float sc = g[oc] * rsqrtf(v[oc] + BN_EPS);
        bnb[nt] = bias[oc]; bns[nt] = sc; bnm[nt] = bt[oc] - m[oc] * sc;
    }
    __syncthreads();

    f32x4 acc[3][4];
#pragma unroll
    for (int r = 0; r < 3; ++r)
#pragma unroll
        for (int nt = 0; nt < 4; ++nt) acc[r][nt] = (f32x4){0.f, 0.f, 0.f, 0.f};

#pragma unroll
    for (int ky = 0; ky < 6; ++ky)
#pragma unroll
        for (int kx = 0; kx < 4; ++kx) {
            int kk = ky * 4 + kx;
            short8 bfr[4];
#pragma unroll
            for (int nt = 0; nt < 4; ++nt)
                bfr[nt] = *(const short8*)(wT + (((size_t)kk * 64 + nt * 16 + n) * 32 + q * 8));
#pragma unroll
            for (int r = 0; r < 3; ++r) {
                int row = 3 * pr + r + ky;
                int col = n + kx;
                short8 afr = *(const short8*)(in_s + (((size_t)row * 20 + col) * 32 + q * 8));
#pragma unroll
                for (int nt = 0; nt < 4; ++nt)
                    acc[r][nt] = __builtin_amdgcn_mfma_f32_16x16x32_bf16(afr, bfr[nt], acc[r][nt], 0, 0, 0);
            }
        }
    size_t ob = (size_t)(nb0 + nl) * 1536;
#pragma unroll
    for (int nt = 0; nt < 4; ++nt) {
        float mx = -3.4e38f;
#pragma unroll
        for (int r = 0; r < 3; ++r)
#pragma unroll
            for (int e = 0; e < 4; ++e) mx = fmaxf(mx, acc[r][nt][e]);
        float val = fmaxf(mx + bnb[nt], 0.f) * bns[nt] + bnm[nt];
        out3[ob + (size_t)(nt * 16 + n) * 24 + pr * 4 + q] = f2bf(val);
    }
}

// ---- fc (MFMA, LDS-free): out = BN(relu(A(M,K)bf16 @ W(N,K)bf16^T + b)) ---
// Block = 4 waves = 32x32 C tile; wave = 16x16 via mfma_16x16x32_bf16.
__global__ __launch_bounds__(256) void fc_m(
    const unsigned short* __restrict__ A, const unsigned short* __restrict__ W,
    const float* __restrict__ bias, const float* __restrict__ g,
    const float* __restrict__ bt, const float* __restrict__ m,
    const float* __restrict__ v, unsigned short* __restrict__ out_b,
    float* __restrict__ out_f, int K, int N, int mode)   // mode 0=bf16, 1=f32
{
    const int tid = threadIdx.x;
    const int lane = tid & 63, wave = tid >> 6;
    const int n = lane & 15, q = lane >> 4;
    const int wr = wave >> 1, wc = wave & 1;
    const int r0 = blockIdx.y * 32 + wr * 16;
    const int c0 = blockIdx.x * 32 + wc * 16;
    const int col = c0 + n;

    float sc = g[col] * rsqrtf(v[col] + BN_EPS);
    float bb = bias[col];
    float mm = bt[col] - m[col] * sc;

    const unsigned short* Ap = A + (size_t)(r0 + n) * K + q * 8;
    const unsigned short* Bp = W + (size_t)col * K + q * 8;

    f32x4 acc = (f32x4){0.f, 0.f, 0.f, 0.f};
    for (int kk = 0; kk < K; kk += 64) {
        short8 a0 = *(const short8*)(Ap + kk);
        short8 b0 = *(const short8*)(Bp + kk);
        short8 a1 = *(const short8*)(Ap + kk + 32);
        short8 b1 = *(const short8*)(Bp + kk + 32);
        acc = __builtin_amdgcn_mfma_f32_16x16x32_bf16(a0, b0, acc, 0, 0, 0);
        acc = __builtin_amdgcn_mfma_f32_16x16x32_bf16(a1, b1, acc, 0, 0, 0);
    }
#pragma unroll
    for (int e = 0; e < 4; ++e) {
        int row = r0 + q * 4 + e;
        float val = fmaxf(acc[e] + bb, 0.f) * sc + mm;
        if (mode == 0) out_b[(size_t)row * N + col] = f2bf(val);
        else           out_f[(size_t)row * N + col] = val;
    }
}

// ---- row L2-normalize; emit sq = sum(e^2) ---------------------------------
__global__ __launch_bounds__(128) void norm_k(const float* __restrict__ f3,
                                              float* __restrict__ E,
                                              float* __restrict__ sq)
{
    __shared__ float red[2];
    const int row = blockIdx.x, tid = threadIdx.x;
    float vv = f3[row * 128 + tid];
    float s = vv * vv;
#pragma unroll
    for (int off = 32; off >= 1; off >>= 1) s += __shfl_down(s, off, 64);
    if ((tid & 63) == 0) red[tid >> 6] = s;
    __syncthreads();
    float total = red[0] + red[1];
    float nn = fmaxf(sqrtf(total), 1e-12f);
    E[row * 128 + tid] = vv / nn;
    if (tid == 0) sq[row] = total / (nn * nn);
}

// ---- pairwise distance + global max ---------------------------------------
__global__ __launch_bounds__(256) void dist_k(const float* __restrict__ E,
                                              const float* __restrict__ sq,
                                              float* __restrict__ D,
                                              unsigned* __restrict__ mxslot)
{
    __shared__ __align__(16) float Ei[16 * 132];
    __shared__ __align__(16) float Ej[16 * 132];
    __shared__ float red[256];
    const int tid = threadIdx.x;
    const int bi = blockIdx.y * 16, bj = blockIdx.x * 16;
    {
        int lr = tid >> 4, lc = (tid & 15) * 8;
        float4 a0 = *(const float4*)(E + (bi + lr) * 128 + lc);
        float4 a1 = *(const float4*)(E + (bi + lr) * 128 + lc + 4);
        *(float4*)(Ei + lr * 132 + lc) = a0;
        *(float4*)(Ei + lr * 132 + lc + 4) = a1;
        float4 b0 = *(const float4*)(E + (bj + lr) * 128 + lc);
        float4 b1 = *(const float4*)(E + (bj + lr) * 128 + lc + 4);
        *(float4*)(Ej + lr * 132 + lc) = b0;
        *(float4*)(Ej + lr * 132 + lc + 4) = b1;
    }
    __syncthreads();
    const int tx = tid & 15, ty = tid >> 4;
    float dot = 0.f;
#pragma unroll 4
    for (int k = 0; k < 128; k += 4) {
        float4 a = *(const float4*)(Ei + ty * 132 + k);
        float4 b = *(const float4*)(Ej + tx * 132 + k);
        dot = fmaf(a.x, b.x, dot); dot = fmaf(a.y, b.y, dot);
        dot = fmaf(a.z, b.z, dot); dot = fmaf(a.w, b.w, dot);
    }
    int i = bi + ty, j = bj + tx;
    float d2 = sq[i] + sq[j] - 2.f * dot;
    float dist = sqrtf(fmaxf(d2, 1e-12f));
    dist = (d2 > 0.f) ? dist : 0.f;
    if (i == j) dist = 0.f;
    D[i * 512 + j] = dist;
    red[tid] = dist;
    __syncthreads();
    for (int s2 = 128; s2 > 0; s2 >>= 1) {
        if (tid < s2) red[tid] = fmaxf(red[tid], red[tid + s2]);
        __syncthreads();
    }
    if (tid == 0) atomicMax(mxslot, __float_as_uint(red[0]));
}

__global__ __launch_bounds__(256) void scale_k(float* __restrict__ D,
                                               const unsigned* __restrict__ mxslot)
{
    int idx = blockIdx.x * 256 + threadIdx.x;
    float M = __uint_as_float(*mxslot);
    D[idx] = D[idx] / M;
}

// ---------------------------------------------------------------------------
extern "C" void kernel_launch(void* const* d_in, const int* in_sizes, int n_in,
                              void* d_out, int out_size, void* d_ws, size_t ws_size,
                              hipStream_t stream)
{
    (void)in_sizes; (void)n_in; (void)out_size;
    const float* x    = (const float*)d_in[0];
    const float* c1w  = (const float*)d_in[1];
    const float* c1b  = (const float*)d_in[2];
    const float* g1   = (const float*)d_in[3];
    const float* b1   = (const float*)d_in[4];
    const float* m1   = (const float*)d_in[5];
    const float* v1   = (const float*)d_in[6];
    const float* c2w  = (const float*)d_in[7];
    const float* c2b  = (const float*)d_in[8];
    const float* g2   = (const float*)d_in[9];
    const float* b2   = (const float*)d_in[10];
    const float* m2   = (const float*)d_in[11];
    const float* v2   = (const float*)d_in[12];
    const float* c3w  = (const float*)d_in[13];
    const float* c3b  = (const float*)d_in[14];
    const float* g3   = (const float*)d_in[15];
    const float* b3   = (const float*)d_in[16];
    const float* m3   = (const float*)d_in[17];
    const float* v3   = (const float*)d_in[18];
    const float* fw1  = (const float*)d_in[19];
    const float* fb1  = (const float*)d_in[20];
    const float* gf1  = (const float*)d_in[21];
    const float* bf1  = (const float*)d_in[22];
    const float* mf1  = (const float*)d_in[23];
    const float* vf1  = (const float*)d_in[24];
    const float* fw2  = (const float*)d_in[25];
    const float* fb2  = (const float*)d_in[26];
    const float* gf2  = (const float*)d_in[27];
    const float* bf2  = (const float*)d_in[28];
    const float* mf2  = (const float*)d_in[29];
    const float* vf2  = (const float*)d_in[30];
    const float* fw3  = (const float*)d_in[31];
    const float* fb3  = (const float*)d_in[32];
    const float* gf3  = (const float*)d_in[33];
    const float* bf3  = (const float*)d_in[34];
    const float* mf3  = (const float*)d_in[35];
    const float* vf3  = (const float*)d_in[36];

    float* ws = (float*)d_ws;
    // ---- persistent region (float offsets, all 16B-aligned) ---------------
    float* f3v  = ws + 0;            // 65536
    float* E    = ws + 65536;        // 65536
    float* sq   = ws + 131072;       // 512
    unsigned* mx = (unsigned*)(ws + 131584);
    unsigned short* wT2b = (unsigned short*)(ws + 131600);   // 12288 ush
    unsigned short* wT3b = (unsigned short*)(ws + 137744);   // 49152 ush
    unsigned short* fw1b = (unsigned short*)(ws + 162320);   // 786432 ush
    unsigned short* fw2b = (unsigned short*)(ws + 555536);   // 131072 ush
    unsigned short* fw3b = (unsigned short*)(ws + 621072);   // 32768 ush
    unsigned short* out3b= (unsigned short*)(ws + 637456);   // 786432 ush
    unsigned short* a1b  = (unsigned short*)(ws + 1030672);  // 262144 ush
    unsigned short* a2b  = (unsigned short*)(ws + 1161744);  // 131072 ush
    const size_t CH0 = 1227280;      // chunk region start (~4.9 MB persistent)

    // chunk bytes/batch: out1c 41*36*16*2 = 47232, out2c 24*20*32*2 = 30720
    int Bc = 512;
    while (Bc > 4 && (size_t)CH0 * 4 + (size_t)Bc * 77952 > ws_size) Bc >>= 1;
    unsigned short* out1c = (unsigned short*)(ws + CH0);
    unsigned short* out2c = out1c + (size_t)Bc * 23616;

    float* out = (float*)d_out;

    hipMemsetAsync(mx, 0, 4, stream);
    repack_k<<<3072, 256, 0, stream>>>(c2w, c3w, fw1, fw2, fw3,
                                       wT2b, wT3b, fw1b, fw2b, fw3b);
    for (int nb0 = 0; nb0 < 512; nb0 += Bc) {
        conv1_k<<<Bc, 384, 0, stream>>>(x, c1w, c1b, g1, b1, m1, v1, out1c, nb0);
        conv2_m<<<Bc, 256, 0, stream>>>(out1c, wT2b, c2b, g2, b2, m2, v2, out2c);
        conv3_m<<<Bc, 384, 0, stream>>>(out2c, wT3b, c3b, g3, b3, m3, v3, out3b, nb0);
    }
    fc_m<<<dim3(16, 16), 256, 0, stream>>>(out3b, fw1b, fb1, gf1, bf1, mf1, vf1,
                                           a1b, nullptr, 1536, 512, 0);
    fc_m<<<dim3(8, 16), 256, 0, stream>>>(a1b, fw2b, fb2, gf2, bf2, mf2, vf2,
                                          a2b, nullptr, 512, 256, 0);
    fc_m<<<dim3(4, 16), 256, 0, stream>>>(a2b, fw3b, fb3, gf3, bf3, mf3, vf3,
                                          nullptr, f3v, 256, 128, 1);
    norm_k<<<512, 128, 0, stream>>>(f3v, E, sq);
    dist_k<<<dim3(32, 32), 256, 0, stream>>>(E, sq, out, mx);
    scale_k<<<1024, 256, 0, stream>>>(out, mx);
}

// Round 7
// 239.463 us; speedup vs baseline: 67.0757x; 1.1253x over previous
//
#include <hip/hip_runtime.h>
#include <hip/hip_bf16.h>
#include <math.h>

// ---------------------------------------------------------------------------
// Round 7: conv1 -> implicit-GEMM bf16 MFMA. M = conv positions ordered
// pooled*4+quad (so a lane's 4 C-regs = one 2x2 pool window), N = 16 oc,
// K = 24 taps zero-padded to 32 (1 MFMA per 16-pos tile). A-frags read from
// a zero-padded fp32 LDS image + a +1-col shifted twin copy => every strip
// is 8B-aligned float2 pairs, no guards. B-frag loaded once per wave.
// conv2/conv3/fc/norm/dist unchanged from R6 (proven).
// ---------------------------------------------------------------------------

#define BN_EPS 1e-5f

typedef __attribute__((ext_vector_type(8))) short short8;   // 8 bf16 = 4 VGPR
typedef __attribute__((ext_vector_type(4))) float f32x4;

__device__ __forceinline__ unsigned short f2bf(float f) {
    unsigned u = __float_as_uint(f);
    u += 0x7fffu + ((u >> 16) & 1u);          // round-to-nearest-even
    return (unsigned short)(u >> 16);
}

__device__ __forceinline__ unsigned pkbf(float a, float b) {
    __hip_bfloat162 h = __float22bfloat162_rn(make_float2(a, b));
    return *reinterpret_cast<unsigned*>(&h);   // v_cvt_pk_bf16_f32
}

// ---- weight repack + fc-weight bf16 cast ----------------------------------
// wT1b[oc 16][k 32] bf16, k=ky*4+kx (<24), pad 0                   (512)
// wT2b[kk=ky*2+kxp][oc 32][k 32] bf16, k=hi*16+ic <-> kx=2*kxp+hi (12288)
// wT3b[kk=ky*4+kx ][oc 64][ic 32] bf16                            (49152)
__global__ __launch_bounds__(256) void repack_k(
    const float* __restrict__ w1, const float* __restrict__ w2,
    const float* __restrict__ w3,
    const float* __restrict__ fw1, const float* __restrict__ fw2,
    const float* __restrict__ fw3,
    unsigned short* __restrict__ wT1b,
    unsigned short* __restrict__ wT2b, unsigned short* __restrict__ wT3b,
    unsigned short* __restrict__ fw1b, unsigned short* __restrict__ fw2b,
    unsigned short* __restrict__ fw3b)
{
    int t = blockIdx.x * 256 + threadIdx.x;
    if (t < 512) {
        int k = t & 31, oc = t >> 5;
        wT1b[t] = (k < 24) ? f2bf(w1[oc * 24 + k]) : (unsigned short)0;
    }
    if (t < 12288) {
        int k = t & 31, oc = (t >> 5) & 31, kk = t >> 10;
        int ky = kk >> 1, kxp = kk & 1;
        int hi = k >> 4, ic = k & 15;
        int kx = 2 * kxp + hi;
        wT2b[t] = f2bf(w2[((oc * 16 + ic) * 6 + ky) * 4 + kx]);
    }
    if (t < 49152) {
        int ic = t & 31, oc = (t >> 5) & 63, kk = t >> 11;
        int ky = kk >> 2, kx = kk & 3;
        wT3b[t] = f2bf(w3[((oc * 32 + ic) * 6 + ky) * 4 + kx]);
    }
    if (t < 786432) fw1b[t] = f2bf(fw1[t]);
    if (t < 131072) fw2b[t] = f2bf(fw2[t]);
    if (t < 32768)  fw3b[t] = f2bf(fw3[t]);
}

// ---- conv1 (MFMA): x(n,1,72,64) fp32 -> out1c padded HWC bf16 [41][36][16]
__global__ __launch_bounds__(256) void conv1_mf(
    const float* __restrict__ x, const unsigned short* __restrict__ wT1,
    const float* __restrict__ bias, const float* __restrict__ g,
    const float* __restrict__ bt, const float* __restrict__ m,
    const float* __restrict__ v, unsigned short* __restrict__ out1,
    int nb0)
{
    // pa[row][c] = img[row-2][c-1], pb[row][c] = img[row-2][c-2]; rows 0..78
    __shared__ __align__(16) float pa[79 * 68];
    __shared__ __align__(16) float pb[79 * 68];
    const int tid = threadIdx.x, nl = blockIdx.x;
    {   // zero both copies (pads + k>=24 ghost rows must be 0)
        float2 z2 = make_float2(0.f, 0.f);
        float2* za = (float2*)pa; float2* zb = (float2*)pb;
        for (int i = tid; i < 2686; i += 256) { za[i] = z2; zb[i] = z2; }
    }
    unsigned short* ob = out1 + (size_t)nl * 23616;
    {   // zero out1c pad cells (conv2 stages the full padded buffer)
        uint4 z; z.x = z.y = z.z = z.w = 0u;
        for (int pc = tid; pc < 324; pc += 256) {
            int row, colc;
            if (pc < 180) { row = pc / 36; colc = pc % 36; if (row >= 2) row += 36; }
            else { int pz = pc - 180; row = 2 + (pz >> 2); colc = (pz & 3) ? 32 + (pz & 3) : 0; }
            uint4* d = (uint4*)(ob + ((size_t)row * 36 + colc) * 16);
            d[0] = z; d[1] = z;
        }
    }
    __syncthreads();
    {   // stage interior
        const float4* src = (const float4*)(x + (size_t)(nb0 + nl) * 4608);
        for (int i = tid; i < 1152; i += 256) {
            float4 val = src[i];
            int f = i * 4;
            int row = (f >> 6) + 2, c = (f & 63) + 1;
            float* a = pa + row * 68 + c;
            a[0] = val.x; a[1] = val.y; a[2] = val.z; a[3] = val.w;
            float2* b = (float2*)(pb + row * 68 + c + 1);    // even idx -> 8B
            b[0] = make_float2(val.x, val.y);
            b[1] = make_float2(val.z, val.w);
        }
    }
    const int lane = tid & 63, wave = tid >> 6;
    const int n = lane & 15, q = lane >> 4;
    float sc = g[n] * rsqrtf(v[n] + BN_EPS);
    float bb = bias[n];
    float mm = bt[n] - m[n] * sc;
    short8 bfr = *(const short8*)(wT1 + n * 32 + q * 8);     // const all tiles
    __syncthreads();

    for (int i = 0; i < 72; ++i) {
        int t = wave * 72 + i;
        // A row mrow = lane&15 = n; position P = 16t + mrow
        int pooled = 4 * t + (n >> 2);
        int ph = pooled >> 5, pw = pooled & 31;
        int py = (n >> 1) & 1, px = n & 1;
        int oh = 2 * ph + py, ow = 2 * pw + px;
        int r0 = (oh + 2 * q) * 68;
        const float* base = px ? (pb + r0 + ow + 1) : (pa + r0 + ow);
        float2 s00 = *(const float2*)(base);
        float2 s01 = *(const float2*)(base + 2);
        float2 s10 = *(const float2*)(base + 68);
        float2 s11 = *(const float2*)(base + 70);
        uint4 uu;
        uu.x = pkbf(s00.x, s00.y); uu.y = pkbf(s01.x, s01.y);
        uu.z = pkbf(s10.x, s10.y); uu.w = pkbf(s11.x, s11.y);
        short8 afr = *reinterpret_cast<short8*>(&uu);
        f32x4 acc = (f32x4){0.f, 0.f, 0.f, 0.f};
        acc = __builtin_amdgcn_mfma_f32_16x16x32_bf16(afr, bfr, acc, 0, 0, 0);
        // C lane: col = n = oc, rows q*4+e -> pooled output 4t+q, pool = max(e)
        int po = 4 * t + q;
        int oph = po >> 5, opw = po & 31;
        float mx = fmaxf(fmaxf(acc[0], acc[1]), fmaxf(acc[2], acc[3]));
        float val = fmaxf(mx + bb, 0.f) * sc + mm;
        ob[((size_t)(oph + 2) * 36 + (opw + 1)) * 16 + n] = f2bf(val);
    }
}

// ---- conv2 (MFMA): out1c [41][36][16] -> out2c padded HWC [24][20][32] ----
__global__ __launch_bounds__(256) void conv2_m(
    const unsigned short* __restrict__ in, const unsigned short* __restrict__ wT,
    const float* __restrict__ bias, const float* __restrict__ g,
    const float* __restrict__ bt, const float* __restrict__ m,
    const float* __restrict__ v, unsigned short* __restrict__ out)
{
    __shared__ __align__(16) unsigned short in_s[41 * 36 * 16];   // 47232 B
    const int tid = threadIdx.x, nl = blockIdx.x;
    {
        const uint4* src = (const uint4*)(in + (size_t)nl * 23616);
        uint4* dst = (uint4*)in_s;
        for (int i = tid; i < 2952; i += 256) dst[i] = src[i];
    }
    unsigned short* ob = out + (size_t)nl * 15360;
    {
        uint4 z; z.x = z.y = z.z = z.w = 0u;
        for (int pc = tid; pc < 192; pc += 256) {
            int row, colc;
            if (pc < 120) { row = pc / 20; colc = pc % 20; if (row >= 2) row += 18; }
            else { int pz = pc - 120; row = 2 + (pz >> 2); colc = (pz & 3) ? 16 + (pz & 3) : 0; }
            uint4* d = (uint4*)(ob + ((size_t)row * 20 + colc) * 32);
            d[0] = z; d[1] = z; d[2] = z; d[3] = z;
        }
    }
    const int lane = tid & 63, wave = tid >> 6;
    const int n = lane & 15, q = lane >> 4;
    float bnb[2], bns[2], bnm[2];
#pragma unroll
    for (int nt = 0; nt < 2; ++nt) {
        int oc = nt * 16 + n;
        float sc = g[oc] * rsqrtf(v[oc] + BN_EPS);
        bnb[nt] = bias[oc]; bns[nt] = sc; bnm[nt] = bt[oc] - m[oc] * sc;
    }
    __syncthreads();

    for (int pass = 0; pass < 3; ++pass) {
        f32x4 acc[3][2][2];
#pragma unroll
        for (int j = 0; j < 3; ++j)
#pragma unroll
            for (int ab = 0; ab < 2; ++ab)
#pragma unroll
                for (int nt = 0; nt < 2; ++nt)
                    acc[j][ab][nt] = (f32x4){0.f, 0.f, 0.f, 0.f};

#pragma unroll
        for (int ky = 0; ky < 6; ++ky)
#pragma unroll
            for (int kxp = 0; kxp < 2; ++kxp) {
                int kk = ky * 2 + kxp;
                short8 bfr[2];
#pragma unroll
                for (int nt = 0; nt < 2; ++nt)
                    bfr[nt] = *(const short8*)(wT + (((size_t)kk * 32 + nt * 16 + n) * 32 + q * 8));
#pragma unroll
                for (int j = 0; j < 3; ++j) {
                    int pp = wave + 4 * (pass * 3 + j);
                    int ph = pp >> 1, half = pp & 1;
                    int col = half * 16 + n + 2 * kxp;
#pragma unroll
                    for (int ab = 0; ab < 2; ++ab) {
                        int row = 2 * ph + ab + ky;
                        short8 afr = *(const short8*)(in_s + (((size_t)row * 36 + col) * 16 + q * 8));
                        acc[j][ab][0] = __builtin_amdgcn_mfma_f32_16x16x32_bf16(afr, bfr[0], acc[j][ab][0], 0, 0, 0);
                        acc[j][ab][1] = __builtin_amdgcn_mfma_f32_16x16x32_bf16(afr, bfr[1], acc[j][ab][1], 0, 0, 0);
                    }
                }
            }
#pragma unroll
        for (int j = 0; j < 3; ++j) {
            int pp = wave + 4 * (pass * 3 + j);
            int ph = pp >> 1, half = pp & 1;
            int pw0 = half * 8 + q * 2;
#pragma unroll
            for (int nt = 0; nt < 2; ++nt) {
                int oc = nt * 16 + n;
                float p0 = fmaxf(fmaxf(acc[j][0][nt][0], acc[j][0][nt][1]),
                                 fmaxf(acc[j][1][nt][0], acc[j][1][nt][1]));
                float p1 = fmaxf(fmaxf(acc[j][0][nt][2], acc[j][0][nt][3]),
                                 fmaxf(acc[j][1][nt][2], acc[j][1][nt][3]));
                p0 = fmaxf(p0 + bnb[nt], 0.f) * bns[nt] + bnm[nt];
                p1 = fmaxf(p1 + bnb[nt], 0.f) * bns[nt] + bnm[nt];
                ob[((size_t)(ph + 2) * 20 + (pw0 + 1)) * 32 + oc] = f2bf(p0);
                ob[((size_t)(ph + 2) * 20 + (pw0 + 2)) * 32 + oc] = f2bf(p1);
            }
        }
    }
}

// ---- conv3 (MFMA): out2c [24][20][32] -> out3 flat (512,1536) bf16 --------
__global__ __launch_bounds__(384) void conv3_m(
    const unsigned short* __restrict__ in, const unsigned short* __restrict__ wT,
    const float* __restrict__ bias, const float* __restrict__ g,
    const float* __restrict__ bt, const float* __restrict__ m,
    const float* __restrict__ v, unsigned short* __restrict__ out3, int nb0)
{
    __shared__ __align__(16) unsigned short in_s[24 * 20 * 32];   // 30720 B
    const int tid = threadIdx.x, nl = blockIdx.x;
    {
        const uint4* src = (const uint4*)(in + (size_t)nl * 15360);
        uint4* dst = (uint4*)in_s;
        for (int i = tid; i < 1920; i += 384) dst[i] = src[i];
    }
    const int lane = tid & 63, pr = tid >> 6;
    const int n = lane & 15, q = lane >> 4;
    float bnb[4], bns[4], bnm[4];
#pragma unroll
    for (int nt = 0; nt < 4; ++nt) {
        int oc = nt * 16 + n;
        float sc = g[oc] * rsqrtf(v[oc] + BN_EPS);
        bnb[nt] = bias[oc]; bns[nt] = sc; bnm[nt] = bt[oc] - m[oc] * sc;
    }
    __syncthreads();

    f32x4 acc[3][4];
#pragma unroll
    for (int r = 0; r < 3; ++r)
#pragma unroll
        for (int nt = 0; nt < 4; ++nt) acc[r][nt] = (f32x4){0.f, 0.f, 0.f, 0.f};

#pragma unroll
    for (int ky = 0; ky < 6; ++ky)
#pragma unroll
        for (int kx = 0; kx < 4; ++kx) {
            int kk = ky * 4 + kx;
            short8 bfr[4];
#pragma unroll
            for (int nt = 0; nt < 4; ++nt)
                bfr[nt] = *(const short8*)(wT + (((size_t)kk * 64 + nt * 16 + n) * 32 + q * 8));
#pragma unroll
            for (int r = 0; r < 3; ++r) {
                int row = 3 * pr + r + ky;
                int col = n + kx;
                short8 afr = *(const short8*)(in_s + (((size_t)row * 20 + col) * 32 + q * 8));
#pragma unroll
                for (int nt = 0; nt < 4; ++nt)
                    acc[r][nt] = __builtin_amdgcn_mfma_f32_16x16x32_bf16(afr, bfr[nt], acc[r][nt], 0, 0, 0);
            }
        }
    size_t ob = (size_t)(nb0 + nl) * 1536;
#pragma unroll
    for (int nt = 0; nt < 4; ++nt) {
        float mx = -3.4e38f;
#pragma unroll
        for (int r = 0; r < 3; ++r)
#pragma unroll
            for (int e = 0; e < 4; ++e) mx = fmaxf(mx, acc[r][nt][e]);
        float val = fmaxf(mx + bnb[nt], 0.f) * bns[nt] + bnm[nt];
        out3[ob + (size_t)(nt * 16 + n) * 24 + pr * 4 + q] = f2bf(val);
    }
}

// ---- fc (MFMA, LDS-free): out = BN(relu(A(M,K)bf16 @ W(N,K)bf16^T + b)) ---
__global__ __launch_bounds__(256) void fc_m(
    const unsigned short* __restrict__ A, const unsigned short* __restrict__ W,
    const float* __restrict__ bias, const float* __restrict__ g,
    const float* __restrict__ bt, const float* __restrict__ m,
    const float* __restrict__ v, unsigned short* __restrict__ out_b,
    float* __restrict__ out_f, int K, int N, int mode)   // mode 0=bf16, 1=f32
{
    const int tid = threadIdx.x;
    const int lane = tid & 63, wave = tid >> 6;
    const int n = lane & 15, q = lane >> 4;
    const int wr = wave >> 1, wc = wave & 1;
    const int r0 = blockIdx.y * 32 + wr * 16;
    const int c0 = blockIdx.x * 32 + wc * 16;
    const int col = c0 + n;

    float sc = g[col] * rsqrtf(v[col] + BN_EPS);
    float bb = bias[col];
    float mm = bt[col] - m[col] * sc;

    const unsigned short* Ap = A + (size_t)(r0 + n) * K + q * 8;
    const unsigned short* Bp = W + (size_t)col * K + q * 8;

    f32x4 acc = (f32x4){0.f, 0.f, 0.f, 0.f};
    for (int kk = 0; kk < K; kk += 64) {
        short8 a0 = *(const short8*)(Ap + kk);
        short8 b0 = *(const short8*)(Bp + kk);
        short8 a1 = *(const short8*)(Ap + kk + 32);
        short8 b1 = *(const short8*)(Bp + kk + 32);
        acc = __builtin_amdgcn_mfma_f32_16x16x32_bf16(a0, b0, acc, 0, 0, 0);
        acc = __builtin_amdgcn_mfma_f32_16x16x32_bf16(a1, b1, acc, 0, 0, 0);
    }
#pragma unroll
    for (int e = 0; e < 4; ++e) {
        int row = r0 + q * 4 + e;
        float val = fmaxf(acc[e] + bb, 0.f) * sc + mm;
        if (mode == 0) out_b[(size_t)row * N + col] = f2bf(val);
        else           out_f[(size_t)row * N + col] = val;
    }
}

// ---- row L2-normalize; emit sq = sum(e^2) ---------------------------------
__global__ __launch_bounds__(128) void norm_k(const float* __restrict__ f3,
                                              float* __restrict__ E,
                                              float* __restrict__ sq)
{
    __shared__ float red[2];
    const int row = blockIdx.x, tid = threadIdx.x;
    float vv = f3[row * 128 + tid];
    float s = vv * vv;
#pragma unroll
    for (int off = 32; off >= 1; off >>= 1) s += __shfl_down(s, off, 64);
    if ((tid & 63) == 0) red[tid >> 6] = s;
    __syncthreads();
    float total = red[0] + red[1];
    float nn = fmaxf(sqrtf(total), 1e-12f);
    E[row * 128 + tid] = vv / nn;
    if (tid == 0) sq[row] = total / (nn * nn);
}

// ---- pairwise distance + global max ---------------------------------------
__global__ __launch_bounds__(256) void dist_k(const float* __restrict__ E,
                                              const float* __restrict__ sq,
                                              float* __restrict__ D,
                                              unsigned* __restrict__ mxslot)
{
    __shared__ __align__(16) float Ei[16 * 132];
    __shared__ __align__(16) float Ej[16 * 132];
    __shared__ float red[256];
    const int tid = threadIdx.x;
    const int bi = blockIdx.y * 16, bj = blockIdx.x * 16;
    {
        int lr = tid >> 4, lc = (tid & 15) * 8;
        float4 a0 = *(const float4*)(E + (bi + lr) * 128 + lc);
        float4 a1 = *(const float4*)(E + (bi + lr) * 128 + lc + 4);
        *(float4*)(Ei + lr * 132 + lc) = a0;
        *(float4*)(Ei + lr * 132 + lc + 4) = a1;
        float4 b0 = *(const float4*)(E + (bj + lr) * 128 + lc);
        float4 b1 = *(const float4*)(E + (bj + lr) * 128 + lc + 4);
        *(float4*)(Ej + lr * 132 + lc) = b0;
        *(float4*)(Ej + lr * 132 + lc + 4) = b1;
    }
    __syncthreads();
    const int tx = tid & 15, ty = tid >> 4;
    float dot = 0.f;
#pragma unroll 4
    for (int k = 0; k < 128; k += 4) {
        float4 a = *(const float4*)(Ei + ty * 132 + k);
        float4 b = *(const float4*)(Ej + tx * 132 + k);
        dot = fmaf(a.x, b.x, dot); dot = fmaf(a.y, b.y, dot);
        dot = fmaf(a.z, b.z, dot); dot = fmaf(a.w, b.w, dot);
    }
    int i = bi + ty, j = bj + tx;
    float d2 = sq[i] + sq[j] - 2.f * dot;
    float dist = sqrtf(fmaxf(d2, 1e-12f));
    dist = (d2 > 0.f) ? dist : 0.f;
    if (i == j) dist = 0.f;
    D[i * 512 + j] = dist;
    red[tid] = dist;
    __syncthreads();
    for (int s2 = 128; s2 > 0; s2 >>= 1) {
        if (tid < s2) red[tid] = fmaxf(red[tid], red[tid + s2]);
        __syncthreads();
    }
    if (tid == 0) atomicMax(mxslot, __float_as_uint(red[0]));
}

__global__ __launch_bounds__(256) void scale_k(float* __restrict__ D,
                                               const unsigned* __restrict__ mxslot)
{
    int idx = blockIdx.x * 256 + threadIdx.x;
    float M = __uint_as_float(*mxslot);
    D[idx] = D[idx] / M;
}

// ---------------------------------------------------------------------------
extern "C" void kernel_launch(void* const* d_in, const int* in_sizes, int n_in,
                              void* d_out, int out_size, void* d_ws, size_t ws_size,
                              hipStream_t stream)
{
    (void)in_sizes; (void)n_in; (void)out_size;
    const float* x    = (const float*)d_in[0];
    const float* c1w  = (const float*)d_in[1];
    const float* c1b  = (const float*)d_in[2];
    const float* g1   = (const float*)d_in[3];
    const float* b1   = (const float*)d_in[4];
    const float* m1   = (const float*)d_in[5];
    const float* v1   = (const float*)d_in[6];
    const float* c2w  = (const float*)d_in[7];
    const float* c2b  = (const float*)d_in[8];
    const float* g2   = (const float*)d_in[9];
    const float* b2   = (const float*)d_in[10];
    const float* m2   = (const float*)d_in[11];
    const float* v2   = (const float*)d_in[12];
    const float* c3w  = (const float*)d_in[13];
    const float* c3b  = (const float*)d_in[14];
    const float* g3   = (const float*)d_in[15];
    const float* b3   = (const float*)d_in[16];
    const float* m3   = (const float*)d_in[17];
    const float* v3   = (const float*)d_in[18];
    const float* fw1  = (const float*)d_in[19];
    const float* fb1  = (const float*)d_in[20];
    const float* gf1  = (const float*)d_in[21];
    const float* bf1  = (const float*)d_in[22];
    const float* mf1  = (const float*)d_in[23];
    const float* vf1  = (const float*)d_in[24];
    const float* fw2  = (const float*)d_in[25];
    const float* fb2  = (const float*)d_in[26];
    const float* gf2  = (const float*)d_in[27];
    const float* bf2  = (const float*)d_in[28];
    const float* mf2  = (const float*)d_in[29];
    const float* vf2  = (const float*)d_in[30];
    const float* fw3  = (const float*)d_in[31];
    const float* fb3  = (const float*)d_in[32];
    const float* gf3  = (const float*)d_in[33];
    const float* bf3  = (const float*)d_in[34];
    const float* mf3  = (const float*)d_in[35];
    const float* vf3  = (const float*)d_in[36];

    float* ws = (float*)d_ws;
    // ---- persistent region (float offsets, all 16B-aligned) ---------------
    float* f3v  = ws + 0;            // 65536
    float* E    = ws + 65536;        // 65536
    float* sq   = ws + 131072;       // 512
    unsigned* mx = (unsigned*)(ws + 131584);
    unsigned short* wT2b = (unsigned short*)(ws + 131600);   // 12288 ush
    unsigned short* wT3b = (unsigned short*)(ws + 137744);   // 49152 ush
    unsigned short* wT1b = (unsigned short*)(ws + 162320);   // 512 ush
    unsigned short* fw1b = (unsigned short*)(ws + 162576);   // 786432 ush
    unsigned short* fw2b = (unsigned short*)(ws + 555792);   // 131072 ush
    unsigned short* fw3b = (unsigned short*)(ws + 621328);   // 32768 ush
    unsigned short* out3b= (unsigned short*)(ws + 637712);   // 786432 ush
    unsigned short* a1b  = (unsigned short*)(ws + 1030928);  // 262144 ush
    unsigned short* a2b  = (unsigned short*)(ws + 1162000);  // 131072 ush
    const size_t CH0 = 1227536;      // chunk region start (~4.9 MB persistent)

    // chunk bytes/batch: out1c 41*36*16*2 = 47232, out2c 24*20*32*2 = 30720
    int Bc = 512;
    while (Bc > 4 && (size_t)CH0 * 4 + (size_t)Bc * 77952 > ws_size) Bc >>= 1;
    unsigned short* out1c = (unsigned short*)(ws + CH0);
    unsigned short* out2c = out1c + (size_t)Bc * 23616;

    float* out = (float*)d_out;

    hipMemsetAsync(mx, 0, 4, stream);
    repack_k<<<3072, 256, 0, stream>>>(c1w, c2w, c3w, fw1, fw2, fw3,
                                       wT1b, wT2b, wT3b, fw1b, fw2b, fw3b);
    for (int nb0 = 0; nb0 < 512; nb0 += Bc) {
        conv1_mf<<<Bc, 256, 0, stream>>>(x, wT1b, c1b, g1, b1, m1, v1, out1c, nb0);
        conv2_m<<<Bc, 256, 0, stream>>>(out1c, wT2b, c2b, g2, b2, m2, v2, out2c);
        conv3_m<<<Bc, 384, 0, stream>>>(out2c, wT3b, c3b, g3, b3, m3, v3, out3b, nb0);
    }
    fc_m<<<dim3(16, 16), 256, 0, stream>>>(out3b, fw1b, fb1, gf1, bf1, mf1, vf1,
                                           a1b, nullptr, 1536, 512, 0);
    fc_m<<<dim3(8, 16), 256, 0, stream>>>(a1b, fw2b, fb2, gf2, bf2, mf2, vf2,
                                          a2b, nullptr, 512, 256, 0);
    fc_m<<<dim3(4, 16), 256, 0, stream>>>(a2b, fw3b, fb3, gf3, bf3, mf3, vf3,
                                          nullptr, f3v, 256, 128, 1);
    norm_k<<<512, 128, 0, stream>>>(f3v, E, sq);
    dist_k<<<dim3(32, 32), 256, 0, stream>>>(E, sq, out, mx);
    scale_k<<<1024, 256, 0, stream>>>(out, mx);
}